// Round 1
// baseline (353.010 us; speedup 1.0000x reference)
//
#include <hip/hip_runtime.h>

#define BATCH   262144
#define IN_DIM  28
#define HID     128
#define LAT     64
#define NCODES  512
#define NBLK    256             // 1024 rows per block (16 waves x 64 rows)
#define WVS     16
#define NWAVE   (NBLK * WVS)    // 4096

// ---- padded LDS table geometry ----
// Row strides chosen so stride_bytes % 128 in {16,48,80,112} (i.e. stride/4 = 4*odd mod 32):
// row-major b64/b128 fragment reads then land 2 lanes per bank (free per m136), and all
// per-read offsets are ADDITIVE (fold into ds_read imm) -- no per-read swizzle VALU.
#define S1 56     // lw1  [128][56]   enc_w1^T, K=32 slot (k>=28 zero)
#define S2 136    // lw2/ld2 [..][136] K=128 slot
#define SC 72     // lcb/ld1 [..][72]  K=64 slot
#define O_LW1 0
#define O_LW2 7168
#define O_LCB 15872
#define O_LD1 52736
#define O_LD2 61952
#define BLOB_SHORTS 66304
#define BLOB_F32    864
#define BLOB_BYTES  (BLOB_SHORTS * 2 + BLOB_F32 * 4)   // 136064
#define LDS_BYTES   BLOB_BYTES

typedef short v4s __attribute__((ext_vector_type(4)));
typedef short v8s __attribute__((ext_vector_type(8)));
typedef float v4f __attribute__((ext_vector_type(4)));

union u2v4 { unsigned u[2]; v4s s; };

__device__ __forceinline__ unsigned short f2bf(float f) {   // RNE (prep only)
  unsigned u = __float_as_uint(f);
  u += 0x7fffu + ((u >> 16) & 1u);
  return (unsigned short)(u >> 16);
}
// pack two truncated bf16 (hi, lo) in ONE v_perm_b32 (truncation validated r7/r8)
__device__ __forceinline__ unsigned pk(float hi, float lo) {
  return __builtin_amdgcn_perm(__float_as_uint(hi), __float_as_uint(lo), 0x07060302u);
}

// 16x16x16 bf16 MFMA: k-index = quad*4+e  -> matches C-layout row = quad*4+r,
// so one stage's accumulator (relu+pk'd) IS the next stage's B-fragment. No LDS transpose.
__device__ __forceinline__ v4f mfma16(v4s a, v4s b, v4f c) {
  return __builtin_amdgcn_mfma_f32_16x16x16bf16_1k(a, b, c, 0, 0, 0);
}
__device__ __forceinline__ v4f mfma32(v8s a, v8s b, v4f c) {
  return __builtin_amdgcn_mfma_f32_16x16x32_bf16(a, b, c, 0, 0, 0);
}

// Blob layout (short offsets), all tables [rows][padded K], pad cols zeroed:
//   lw1 @0      [128 hid][56]   enc_w1^T          (K data 0..31, k>=28 zero)
//   lw2 @7168   [64  lat][136]  enc_w2^T          (K data 0..127)
//   lcb @15872  [512 code][72]  bf16(-2*codebook) (K data 0..63)
//   ld1 @52736  [128 hid][72]   bf16(-0.5*dec_w1^T)  (scale cancels -2q)
//   ld2 @61952  [32  n][136]    dec_w2^T          (rows n>=28 zero)
// f32 @ byte 132608: e2[512], b1[128], b2[64], db1[128], db2[32 pad0]
__global__ __launch_bounds__(256) void vq_prep(
    const float* __restrict__ ew1, const float* __restrict__ eb1,
    const float* __restrict__ ew2, const float* __restrict__ eb2,
    const float* __restrict__ cb,  const float* __restrict__ dw1,
    const float* __restrict__ db1, const float* __restrict__ dw2,
    const float* __restrict__ db2,
    unsigned short* __restrict__ blob) {
  int i = blockIdx.x * 256 + threadIdx.x;
  float* fb = (float*)(blob + BLOB_SHORTS);
  if (i < O_LW2) {                       // lw1 [128][56]
    int row = i / S1, col = i % S1;
    blob[i] = (col < IN_DIM) ? f2bf(ew1[col * HID + row]) : (unsigned short)0;
  } else if (i < O_LCB) {                // lw2 [64][136]
    int j = i - O_LW2; int row = j / S2, col = j % S2;
    blob[i] = (col < HID) ? f2bf(ew2[col * LAT + row]) : (unsigned short)0;
  } else if (i < O_LD1) {                // lcb [512][72] = -2*codebook
    int j = i - O_LCB; int row = j / SC, col = j % SC;
    blob[i] = (col < LAT) ? f2bf(-2.0f * cb[row * LAT + col]) : (unsigned short)0;
  } else if (i < O_LD2) {                // ld1 [128][72] = -0.5*dec_w1^T
    int j = i - O_LD1; int row = j / SC, col = j % SC;
    blob[i] = (col < LAT) ? f2bf(-0.5f * dw1[col * HID + row]) : (unsigned short)0;
  } else if (i < BLOB_SHORTS) {          // ld2 [32][136]
    int j = i - O_LD2; int row = j / S2, col = j % S2;
    blob[i] = (col < HID && row < IN_DIM) ? f2bf(dw2[col * IN_DIM + row]) : (unsigned short)0;
  } else if (i < BLOB_SHORTS + 512) {    // e2
    int c = i - BLOB_SHORTS;
    float s = 0.f;
    for (int d = 0; d < LAT; ++d) { float v = cb[c * LAT + d]; s += v * v; }
    fb[c] = s;
  } else if (i < BLOB_SHORTS + 640) {
    fb[i - BLOB_SHORTS] = eb1[i - BLOB_SHORTS - 512];
  } else if (i < BLOB_SHORTS + 704) {
    fb[i - BLOB_SHORTS] = eb2[i - BLOB_SHORTS - 640];
  } else if (i < BLOB_SHORTS + 832) {
    fb[i - BLOB_SHORTS] = db1[i - BLOB_SHORTS - 704];
  } else if (i < BLOB_SHORTS + 864) {
    int k = i - BLOB_SHORTS - 832;
    fb[i - BLOB_SHORTS] = (k < IN_DIM) ? db2[k] : 0.f;
  }
}

// ---------------- fused main kernel ----------------
// Round-10: register-resident swapped-GEMM chain. Every stage computes the
// TRANSPOSED product (features = D-rows on quad*4+r, batch = D-cols on lm) so the
// 16x16x16 C-layout chains directly into the next stage's B-fragment after an
// in-register relu+pack. All 5 per-tile LDS transpose round-trips of r9 are gone;
// LDS holds read-only tables only (no barriers in the loop). Argmin uses packed
// float keys (dist bits | (ct*4+r) in low 7 mantissa bits) with fmin/min3 and a
// 2-step cross-quad shuffle reduce; recon stores are dwordx4; x regs are reused
// for the loss (no re-read).
__global__ __launch_bounds__(1024) void vq_main(
    const float* __restrict__ x,
    const unsigned short* __restrict__ blob,
    float* __restrict__ out, float* __restrict__ partials) {

  extern __shared__ __align__(16) char smem[];
  const unsigned short* L = (const unsigned short*)smem;
  const float*         LF = (const float*)(smem + BLOB_SHORTS * 2);

  const int tid  = threadIdx.x;
  const int wave = tid >> 6;
  const int lane = tid & 63;
  const int quad = lane >> 4;
  const int lm   = lane & 15;

  // ---- stage tables into LDS (one-time) ----
  {
    const float4* src = (const float4*)blob;
    float4* dst = (float4*)smem;
#pragma unroll
    for (int it = 0; it < 9; ++it) {
      int idx = it * 1024 + tid;
      if (idx < BLOB_BYTES / 16) dst[idx] = src[idx];
    }
  }
  __syncthreads();

  // per-lane A-fragment bases (short offsets); per-read offsets are compile-time imm
  const int aw1 = O_LW1 + lm * S1 + quad * 4;   // b64,  row j*16+lm, k kc*16+quad*4
  const int aw2 = O_LW2 + lm * S2 + quad * 4;   // b64
  const int acb = O_LCB + lm * SC + quad * 4;   // b64
  const int ad1 = O_LD1 + lm * SC + quad * 8;   // b128, k kc*32+quad*8
  const int ad2 = O_LD2 + lm * S2 + quad * 4;   // b64

  const int rbase = blockIdx.x * 1024 + wave * 64;
  float racc = 0.f, vqacc = 0.f;

  // x rows live in regs for: B-frags (stage1), loss (end of tile). dims quad*4..+3 / 16+quad*4..+3
  const float* xp0 = x + (size_t)(rbase + lm) * IN_DIM;
  float4 x0 = *(const float4*)(xp0 + quad * 4);
  float4 x1 = {0.f, 0.f, 0.f, 0.f};
  if (quad < 3) x1 = *(const float4*)(xp0 + 16 + quad * 4);

#pragma unroll 1
  for (int t = 0; t < 4; ++t) {
    const int r0 = rbase + t * 16;

    // pack x B-frags
    u2v4 bx0, bx1;
    bx0.u[0] = pk(x0.y, x0.x); bx0.u[1] = pk(x0.w, x0.z);
    bx1.u[0] = pk(x1.y, x1.x); bx1.u[1] = pk(x1.w, x1.z);

    // prefetch next tile's x (hides global latency under this tile's compute)
    float4 xn0 = x0, xn1 = x1;
    if (t < 3) {
      const float* xq = x + (size_t)(r0 + 16 + lm) * IN_DIM;
      xn0 = *(const float4*)(xq + quad * 4);
      xn1 = (float4){0.f, 0.f, 0.f, 0.f};
      if (quad < 3) xn1 = *(const float4*)(xq + 16 + quad * 4);
    }

    // ---- stages 1+2 fused: H^T j-tile -> immediate z^T K-accumulation (kc=j) ----
    v4f accz[4];
#pragma unroll
    for (int nt = 0; nt < 4; ++nt)
      accz[nt] = *(const v4f*)&LF[640 + nt * 16 + quad * 4];   // b2 seed
#pragma unroll
    for (int j = 0; j < 8; ++j) {
      v4f h = *(const v4f*)&LF[512 + j * 16 + quad * 4];       // b1 seed
      h = mfma16(*(const v4s*)&L[aw1 + j * (16 * S1)     ], bx0.s, h);
      h = mfma16(*(const v4s*)&L[aw1 + j * (16 * S1) + 16], bx1.s, h);
      u2v4 hb;
      hb.u[0] = pk(fmaxf(h[1], 0.f), fmaxf(h[0], 0.f));
      hb.u[1] = pk(fmaxf(h[3], 0.f), fmaxf(h[2], 0.f));
#pragma unroll
      for (int nt = 0; nt < 4; ++nt)
        accz[nt] = mfma16(*(const v4s*)&L[aw2 + nt * (16 * S2) + j * 16], hb.s, accz[nt]);
    }

    // ---- z2 partial (f32 z) + pack z B-frags ----
    float z2l = 0.f;
    v4s zf[4];
#pragma unroll
    for (int nt = 0; nt < 4; ++nt) {
      v4f z = accz[nt];
      z2l += z[0] * z[0] + z[1] * z[1] + z[2] * z[2] + z[3] * z[3];
      u2v4 p; p.u[0] = pk(z[1], z[0]); p.u[1] = pk(z[3], z[2]);
      zf[nt] = p.s;
    }

    // ---- argmin: dist^T = e2 + (-2e)·z, packed-key running min ----
    // key = dist bits with low 7 mantissa bits replaced by (ct*4+r): float order ==
    // dist order (granularity 2^-16 relative, << bf16 input noise); low code wins ties.
    float bk = __uint_as_float(0x7f7fffffu);
#pragma unroll 4
    for (int ct = 0; ct < 32; ++ct) {
      v4f d = *(const v4f*)&LF[ct * 16 + quad * 4];            // e2 seed (broadcast)
      d = mfma16(*(const v4s*)&L[acb + ct * (16 * SC)     ], zf[0], d);
      d = mfma16(*(const v4s*)&L[acb + ct * (16 * SC) + 16], zf[1], d);
      d = mfma16(*(const v4s*)&L[acb + ct * (16 * SC) + 32], zf[2], d);
      d = mfma16(*(const v4s*)&L[acb + ct * (16 * SC) + 48], zf[3], d);
      float k0 = __uint_as_float((__float_as_uint(d[0]) & 0xFFFFFF80u) | (unsigned)(ct * 4 + 0));
      float k1 = __uint_as_float((__float_as_uint(d[1]) & 0xFFFFFF80u) | (unsigned)(ct * 4 + 1));
      float k2 = __uint_as_float((__float_as_uint(d[2]) & 0xFFFFFF80u) | (unsigned)(ct * 4 + 2));
      float k3 = __uint_as_float((__float_as_uint(d[3]) & 0xFFFFFF80u) | (unsigned)(ct * 4 + 3));
      bk = fminf(bk, fminf(fminf(k0, k1), fminf(k2, k3)));
    }

    // ---- cross-quad argmin + z2 reduce (codes split across quads) ----
    int qv = quad;
#pragma unroll
    for (int off = 16; off < 64; off <<= 1) {
      float ok = __shfl_xor(bk, off, 64);
      int   oq = __shfl_xor(qv, off, 64);
      z2l += __shfl_xor(z2l, off, 64);
      if (ok < bk || (ok == bk && oq < qv)) { bk = ok; qv = oq; }
    }
    unsigned kb = __float_as_uint(bk);
    int code = (int)((kb >> 2) & 31u) * 16 + qv * 4 + (int)(kb & 3u);
    if (quad == 0) vqacc += z2l + __uint_as_float(kb & 0xFFFFFF80u);  // ||z-q||^2

    // ---- gather -2q (per-lm row), stages 5+6 fused; ld1 pre-scaled -0.5 cancels ----
    const int gb = O_LCB + code * SC + quad * 8;
    v8s q0 = *(const v8s*)&L[gb];
    v8s q1 = *(const v8s*)&L[gb + 32];
    v4f a60 = *(const v4f*)&LF[832 + quad * 4];                // db2 seeds
    v4f a61 = *(const v4f*)&LF[848 + quad * 4];
#pragma unroll
    for (int j = 0; j < 8; ++j) {
      v4f hd = *(const v4f*)&LF[704 + j * 16 + quad * 4];      // db1 seed
      hd = mfma32(*(const v8s*)&L[ad1 + j * (16 * SC)     ], q0, hd);
      hd = mfma32(*(const v8s*)&L[ad1 + j * (16 * SC) + 32], q1, hd);
      u2v4 hb;
      hb.u[0] = pk(fmaxf(hd[1], 0.f), fmaxf(hd[0], 0.f));
      hb.u[1] = pk(fmaxf(hd[3], 0.f), fmaxf(hd[2], 0.f));
      a60 = mfma16(*(const v4s*)&L[ad2 + j * 16            ], hb.s, a60);
      a61 = mfma16(*(const v4s*)&L[ad2 + 16 * S2 + j * 16  ], hb.s, a61);
    }

    // ---- store recon (dwordx4) + loss partial (x regs reused, no re-read) ----
    {
      float* op = out + (size_t)(r0 + lm) * IN_DIM;
      *(float4*)(op + quad * 4) = (float4){a60[0], a60[1], a60[2], a60[3]};
      if (quad < 3)
        *(float4*)(op + 16 + quad * 4) = (float4){a61[0], a61[1], a61[2], a61[3]};
      float d0 = a60[0] - x0.x, d1 = a60[1] - x0.y, d2 = a60[2] - x0.z, d3 = a60[3] - x0.w;
      racc += d0 * d0 + d1 * d1 + d2 * d2 + d3 * d3;
      // quad3/nt1: ld2 rows 28..31 and db2 pad are zero -> a61==0, x1==0 -> adds 0
      float e0 = a61[0] - x1.x, e1 = a61[1] - x1.y, e2v = a61[2] - x1.z, e3 = a61[3] - x1.w;
      racc += e0 * e0 + e1 * e1 + e2v * e2v + e3 * e3;
    }
    x0 = xn0; x1 = xn1;
  }

  // ---- per-wave butterfly, per-wave partial store (no atomics) ----
#pragma unroll
  for (int off = 1; off < 64; off <<= 1) {
    racc  += __shfl_xor(racc, off, 64);
    vqacc += __shfl_xor(vqacc, off, 64);
  }
  if (lane == 0) {
    size_t w = (size_t)blockIdx.x * WVS + wave;
    partials[w * 2]     = racc;
    partials[w * 2 + 1] = vqacc;
  }
}

// ---------------- finalize: reduce per-wave partials, write scalars ----------------
__global__ __launch_bounds__(256) void vq_fin(const float* __restrict__ partials,
                                              float* __restrict__ out) {
  float r = 0.f, v = 0.f;
  for (int i = threadIdx.x; i < NWAVE; i += 256) {
    r += partials[2 * i];
    v += partials[2 * i + 1];
  }
#pragma unroll
  for (int off = 1; off < 64; off <<= 1) {
    r += __shfl_xor(r, off, 64);
    v += __shfl_xor(v, off, 64);
  }
  __shared__ float s[4][2];
  int w = threadIdx.x >> 6;
  if ((threadIdx.x & 63) == 0) { s[w][0] = r; s[w][1] = v; }
  __syncthreads();
  if (threadIdx.x == 0) {
    float R = s[0][0] + s[1][0] + s[2][0] + s[3][0];
    float V = s[0][1] + s[1][1] + s[2][1] + s[3][1];
    out[7340032] = R * (1.0f / 7340032.0f);          // recon_loss = S / (B*28)
    out[7340033] = V * (1.25f / 16777216.0f);        // vq_loss = 1.25 * S / (B*64)
  }
}

extern "C" void kernel_launch(void* const* d_in, const int* in_sizes, int n_in,
                              void* d_out, int out_size, void* d_ws, size_t ws_size,
                              hipStream_t stream) {
  const float* x   = (const float*)d_in[0];
  const float* ew1 = (const float*)d_in[1];
  const float* eb1 = (const float*)d_in[2];
  const float* ew2 = (const float*)d_in[3];
  const float* eb2 = (const float*)d_in[4];
  const float* cb  = (const float*)d_in[5];
  const float* dw1 = (const float*)d_in[6];
  const float* db1 = (const float*)d_in[7];
  const float* dw2 = (const float*)d_in[8];
  const float* db2 = (const float*)d_in[9];

  char* ws = (char*)d_ws;
  unsigned short* blob = (unsigned short*)(ws + 0);   // 136064 B
  float* partials = (float*)(ws + 136192);            // 32768 B (4096*2 f32)

  float* out = (float*)d_out;

  // allow >64 KB dynamic LDS (gfx950 workgroup max is 160 KB)
  (void)hipFuncSetAttribute((const void*)vq_main,
                            hipFuncAttributeMaxDynamicSharedMemorySize, LDS_BYTES);

  vq_prep<<<263, 256, 0, stream>>>(ew1, eb1, ew2, eb2, cb, dw1, db1, dw2, db2, blob);
  vq_main<<<NBLK, 1024, LDS_BYTES, stream>>>(x, blob, out, partials);
  vq_fin<<<1, 256, 0, stream>>>(partials, out);
}

// Round 2
// 296.777 us; speedup vs baseline: 1.1895x; 1.1895x over previous
//
#include <hip/hip_runtime.h>

#define BATCH   262144
#define IN_DIM  28
#define HID     128
#define LAT     64
#define NCODES  512
#define NBLK    256             // 1024 rows per block (16 waves x 64 rows)
#define WVS     16
#define NWAVE   (NBLK * WVS)    // 4096

// ---- quad-grouped LDS table geometry ----
// Element (row,k) stored at row*S + q'*(K/4) + j*4 + e where k = j*16 + q'*4 + e.
// A lane (lm, quad) reading its mfma16 A-frags for ALL k-chunks of a row reads
// K/4 CONTIGUOUS shorts at row*S + quad*(K/4): pure ds_read_b128, 16B-aligned
// (S multiple of 8 shorts), additive compile-time offsets. Strides 40/72/136
// shorts (80/144/272 B) put exactly 8 of the wave's 64 16B-accesses on every
// bank (uniform coverage, standard GEMM pattern).
#define S1 40     // lw1  [128][40]  K=32  (k>=28 zero)
#define S2 136    // lw2/ld2 [..][136] K=128
#define SC 72     // lcb/ld1 [..][72]  K=64
#define O_LW1 0
#define O_LW2 5120
#define O_LCB 13824
#define O_LD1 50688
#define O_LD2 59904
#define BLOB_SHORTS 64256
#define BLOB_F32    864
#define BLOB_BYTES  (BLOB_SHORTS * 2 + BLOB_F32 * 4)   // 131968
#define LDS_BYTES   BLOB_BYTES

typedef short v4s __attribute__((ext_vector_type(4)));
typedef short v8s __attribute__((ext_vector_type(8)));
typedef float v4f __attribute__((ext_vector_type(4)));

union u2v4 { unsigned u[2]; v4s s; };

__device__ __forceinline__ unsigned short f2bf(float f) {   // RNE (prep only)
  unsigned u = __float_as_uint(f);
  u += 0x7fffu + ((u >> 16) & 1u);
  return (unsigned short)(u >> 16);
}
// pack two truncated bf16 (hi, lo) in ONE v_perm_b32 (truncation validated r7/r8)
__device__ __forceinline__ unsigned pk(float hi, float lo) {
  return __builtin_amdgcn_perm(__float_as_uint(hi), __float_as_uint(lo), 0x07060302u);
}

// 16x16x16 bf16 MFMA: k-index = quad*4+e matches C-layout row = quad*4+r,
// so one stage's accumulator (relu+pk'd) IS the next stage's B-fragment.
__device__ __forceinline__ v4f mfma16(v4s a, v4s b, v4f c) {
  return __builtin_amdgcn_mfma_f32_16x16x16bf16_1k(a, b, c, 0, 0, 0);
}
__device__ __forceinline__ v4s lo4(v8s v) { return __builtin_shufflevector(v, v, 0, 1, 2, 3); }
__device__ __forceinline__ v4s hi4(v8s v) { return __builtin_shufflevector(v, v, 4, 5, 6, 7); }

__device__ __forceinline__ v4s rlpk(v4f h) {   // relu + pack to bf16 chunk
  u2v4 c;
  c.u[0] = pk(fmaxf(h[1], 0.f), fmaxf(h[0], 0.f));
  c.u[1] = pk(fmaxf(h[3], 0.f), fmaxf(h[2], 0.f));
  return c.s;
}
__device__ __forceinline__ v4s zpk(v4f z) {    // pack to bf16 chunk
  u2v4 c; c.u[0] = pk(z[1], z[0]); c.u[1] = pk(z[3], z[2]); return c.s;
}
// argmin key: dist upper bits | 9-bit code (float order == dist order to 2^-14 rel;
// lowest code wins ties among equal upper bits)
__device__ __forceinline__ float kpack(float d, unsigned code) {
  return __uint_as_float((__float_as_uint(d) & 0xFFFFFE00u) | code);
}

// Blob layout (short offsets), quad-grouped, pad zeroed:
//   lw1 @0      [128 hid][40]   enc_w1^T   (K=32 slot, k>=28 zero)
//   lw2 @5120   [64  lat][136]  enc_w2^T   (K=128)
//   lcb @13824  [512 code][72]  bf16(-2*codebook) (K=64)
//   ld1 @50688  [128 hid][72]   bf16(-0.5*dec_w1^T)  (scale cancels -2q)
//   ld2 @59904  [32  n][136]    dec_w2^T   (rows n>=28 zero)
// f32 @ byte 128512: e2[512], b1[128], b2[64], db1[128], db2[32 pad0]
__global__ __launch_bounds__(256) void vq_prep(
    const float* __restrict__ ew1, const float* __restrict__ eb1,
    const float* __restrict__ ew2, const float* __restrict__ eb2,
    const float* __restrict__ cb,  const float* __restrict__ dw1,
    const float* __restrict__ db1, const float* __restrict__ dw2,
    const float* __restrict__ db2,
    unsigned short* __restrict__ blob) {
  int i = blockIdx.x * 256 + threadIdx.x;
  float* fb = (float*)(blob + BLOB_SHORTS);
  if (i < O_LW2) {                       // lw1 [128][40] K=32 per=8
    int row = i / S1, s = i % S1;
    unsigned short v = 0;
    if (s < 32) {
      int q = s >> 3, r2 = s & 7, j = r2 >> 2, e = r2 & 3;
      int k = j * 16 + q * 4 + e;
      if (k < IN_DIM) v = f2bf(ew1[k * HID + row]);
    }
    blob[i] = v;
  } else if (i < O_LCB) {                // lw2 [64][136] K=128 per=32
    int j2 = i - O_LW2; int row = j2 / S2, s = j2 % S2;
    unsigned short v = 0;
    if (s < 128) {
      int q = s >> 5, r2 = s & 31, j = r2 >> 2, e = r2 & 3;
      int k = j * 16 + q * 4 + e;
      v = f2bf(ew2[k * LAT + row]);
    }
    blob[i] = v;
  } else if (i < O_LD1) {                // lcb [512][72] K=64 per=16, = -2*cb
    int j2 = i - O_LCB; int row = j2 / SC, s = j2 % SC;
    unsigned short v = 0;
    if (s < 64) {
      int q = s >> 4, r2 = s & 15, j = r2 >> 2, e = r2 & 3;
      int k = j * 16 + q * 4 + e;
      v = f2bf(-2.0f * cb[row * LAT + k]);
    }
    blob[i] = v;
  } else if (i < O_LD2) {                // ld1 [128][72] = -0.5*dec_w1^T
    int j2 = i - O_LD1; int row = j2 / SC, s = j2 % SC;
    unsigned short v = 0;
    if (s < 64) {
      int q = s >> 4, r2 = s & 15, j = r2 >> 2, e = r2 & 3;
      int k = j * 16 + q * 4 + e;
      v = f2bf(-0.5f * dw1[k * HID + row]);
    }
    blob[i] = v;
  } else if (i < BLOB_SHORTS) {          // ld2 [32][136]
    int j2 = i - O_LD2; int row = j2 / S2, s = j2 % S2;
    unsigned short v = 0;
    if (s < 128 && row < IN_DIM) {
      int q = s >> 5, r2 = s & 31, j = r2 >> 2, e = r2 & 3;
      int k = j * 16 + q * 4 + e;
      v = f2bf(dw2[k * IN_DIM + row]);
    }
    blob[i] = v;
  } else if (i < BLOB_SHORTS + 512) {    // e2
    int c = i - BLOB_SHORTS;
    float s = 0.f;
    for (int d = 0; d < LAT; ++d) { float v = cb[c * LAT + d]; s += v * v; }
    fb[c] = s;
  } else if (i < BLOB_SHORTS + 640) {
    fb[i - BLOB_SHORTS] = eb1[i - BLOB_SHORTS - 512];
  } else if (i < BLOB_SHORTS + 704) {
    fb[i - BLOB_SHORTS] = eb2[i - BLOB_SHORTS - 640];
  } else if (i < BLOB_SHORTS + 832) {
    fb[i - BLOB_SHORTS] = db1[i - BLOB_SHORTS - 704];
  } else if (i < BLOB_SHORTS + 864) {
    int k = i - BLOB_SHORTS - 832;
    fb[i - BLOB_SHORTS] = (k < IN_DIM) ? db2[k] : 0.f;
  }
}

// ---------------- fused main kernel ----------------
// Round-11: register-resident swapped-GEMM chain (r10) + the two fixes its
// counters demanded:
//  * __launch_bounds__(1024, 4): dynamic-LDS blinds the compiler (it targeted
//    8 waves/EU -> 64 VGPRs -> ~700 MB scratch spill traffic, the whole r10
//    regression). 4 waves/EU = the real occupancy (1 block/CU at 132 KB LDS)
//    -> 128-VGPR budget, no spills.
//  * 2-tile sweeps + quad-grouped tables: every weight/codebook fragment read
//    (all ds_read_b128 now) is shared by TWO 16-row batch tiles, halving LDS
//    table bytes per row -- the LDS pipe, not VALU/MFMA, is the structural
//    floor (~114 KB table reads per 16 rows otherwise).
__global__ __launch_bounds__(1024, 4) void vq_main(
    const float* __restrict__ x,
    const unsigned short* __restrict__ blob,
    float* __restrict__ out, float* __restrict__ partials) {

  extern __shared__ __align__(16) char smem[];
  const unsigned short* L = (const unsigned short*)smem;
  const float*         LF = (const float*)(smem + BLOB_SHORTS * 2);

  const int tid  = threadIdx.x;
  const int wave = tid >> 6;
  const int lane = tid & 63;
  const int quad = lane >> 4;
  const int lm   = lane & 15;

  // ---- stage tables into LDS (one-time) ----
  {
    const float4* src = (const float4*)blob;
    float4* dst = (float4*)smem;
#pragma unroll
    for (int it = 0; it < 9; ++it) {
      int idx = it * 1024 + tid;
      if (idx < BLOB_BYTES / 16) dst[idx] = src[idx];
    }
  }
  __syncthreads();

  // per-lane fragment bases (short offsets); per-read offsets compile-time imm
  const int fw1 = O_LW1 + lm * S1 + quad * 8;    // + j*(16*S1)
  const int fw2 = O_LW2 + lm * S2 + quad * 32;   // + nt*(16*S2) + jp*8
  const int fcb = O_LCB + lm * SC + quad * 16;   // + ct*(16*SC) (+8)
  const int fd1 = O_LD1 + lm * SC + quad * 16;   // + j*(16*SC) (+8)
  const int fd2 = O_LD2 + lm * S2 + quad * 32;   // + nt*(16*S2) + jp*8

  const int rbase = blockIdx.x * 1024 + wave * 64;
  float racc = 0.f, vqacc = 0.f;

  for (int sw = 0; sw < 2; ++sw) {
    const int r0 = rbase + sw * 32;

    // ---- x load (f32 kept for loss), bf16 pack (chunks c0/c1) ----
    const float* xpa = x + (size_t)(r0 + lm) * IN_DIM;
    const float* xpb = x + (size_t)(r0 + 16 + lm) * IN_DIM;
    float4 xa0 = *(const float4*)(xpa + quad * 4);
    float4 xb0 = *(const float4*)(xpb + quad * 4);
    float4 xa1 = {0.f, 0.f, 0.f, 0.f}, xb1 = xa1;
    if (quad < 3) {
      xa1 = *(const float4*)(xpa + 16 + quad * 4);
      xb1 = *(const float4*)(xpb + 16 + quad * 4);
    }
    v4s bxa0 = zpk((v4f){xa0.x, xa0.y, xa0.z, xa0.w});
    v4s bxa1 = zpk((v4f){xa1.x, xa1.y, xa1.z, xa1.w});
    v4s bxb0 = zpk((v4f){xb0.x, xb0.y, xb0.z, xb0.w});
    v4s bxb1 = zpk((v4f){xb1.x, xb1.y, xb1.z, xb1.w});

    // ---- stages 1+2 fused, both tiles share every weight fragment ----
    v4f za[4], zb[4];
#pragma unroll
    for (int nt = 0; nt < 4; ++nt) {
      v4f s0 = *(const v4f*)&LF[640 + nt * 16 + quad * 4];   // b2 seed
      za[nt] = s0; zb[nt] = s0;
    }
#pragma unroll
    for (int jp = 0; jp < 4; ++jp) {
      v4s hA[2], hB[2];
#pragma unroll
      for (int jj = 0; jj < 2; ++jj) {
        int j = jp * 2 + jj;
        v8s w = *(const v8s*)&L[fw1 + j * (16 * S1)];
        v4f sd = *(const v4f*)&LF[512 + j * 16 + quad * 4];  // b1 seed
        v4f ha = mfma16(lo4(w), bxa0, sd);
        ha = mfma16(hi4(w), bxa1, ha);
        v4f hb = mfma16(lo4(w), bxb0, sd);
        hb = mfma16(hi4(w), bxb1, hb);
        hA[jj] = rlpk(ha); hB[jj] = rlpk(hb);
      }
#pragma unroll
      for (int nt = 0; nt < 4; ++nt) {
        v8s w2 = *(const v8s*)&L[fw2 + nt * (16 * S2) + jp * 8];
        za[nt] = mfma16(lo4(w2), hA[0], za[nt]);
        za[nt] = mfma16(hi4(w2), hA[1], za[nt]);
        zb[nt] = mfma16(lo4(w2), hB[0], zb[nt]);
        zb[nt] = mfma16(hi4(w2), hB[1], zb[nt]);
      }
    }

    // ---- z2 partial (f32 z) + pack z B-frags ----
    float z2a = 0.f, z2b = 0.f;
    v4s zfa[4], zfb[4];
#pragma unroll
    for (int nt = 0; nt < 4; ++nt) {
      v4f z = za[nt];
      z2a += z[0] * z[0] + z[1] * z[1] + z[2] * z[2] + z[3] * z[3];
      zfa[nt] = zpk(z);
      z = zb[nt];
      z2b += z[0] * z[0] + z[1] * z[1] + z[2] * z[2] + z[3] * z[3];
      zfb[nt] = zpk(z);
    }

    // ---- argmin: dist^T = e2 + (-2e)·z; cb fragments shared by both tiles ----
    float bkA = __uint_as_float(0x7f7fffffu);
    float bkB = bkA;
#pragma unroll 2
    for (int ct = 0; ct < 32; ++ct) {
      v8s c0 = *(const v8s*)&L[fcb + ct * (16 * SC)];        // chunks 0,1
      v8s c1 = *(const v8s*)&L[fcb + ct * (16 * SC) + 8];    // chunks 2,3
      v4f sd = *(const v4f*)&LF[ct * 16 + quad * 4];         // e2 seed
      v4f dA = mfma16(lo4(c0), zfa[0], sd);
      dA = mfma16(hi4(c0), zfa[1], dA);
      dA = mfma16(lo4(c1), zfa[2], dA);
      dA = mfma16(hi4(c1), zfa[3], dA);
      v4f dB = mfma16(lo4(c0), zfb[0], sd);
      dB = mfma16(hi4(c0), zfb[1], dB);
      dB = mfma16(lo4(c1), zfb[2], dB);
      dB = mfma16(hi4(c1), zfb[3], dB);
#pragma unroll
      for (int r = 0; r < 4; ++r) {
        unsigned code = (unsigned)(ct * 16 + quad * 4 + r);
        bkA = fminf(bkA, kpack(dA[r], code));
        bkB = fminf(bkB, kpack(dB[r], code));
      }
    }

    // ---- cross-quad argmin + z2 reduce ----
#pragma unroll
    for (int off = 16; off < 64; off <<= 1) {
      bkA = fminf(bkA, __shfl_xor(bkA, off, 64));
      bkB = fminf(bkB, __shfl_xor(bkB, off, 64));
      z2a += __shfl_xor(z2a, off, 64);
      z2b += __shfl_xor(z2b, off, 64);
    }
    unsigned ka = __float_as_uint(bkA), kb = __float_as_uint(bkB);
    int codeA = (int)(ka & 511u), codeB = (int)(kb & 511u);
    if (quad == 0)
      vqacc += z2a + __uint_as_float(ka & 0xFFFFFE00u)
             + z2b + __uint_as_float(kb & 0xFFFFFE00u);      // ||z-q||^2

    // ---- gather -2q (2x b128 each tile) ----
    const int gA = O_LCB + codeA * SC + quad * 16;
    const int gB = O_LCB + codeB * SC + quad * 16;
    v8s qa0 = *(const v8s*)&L[gA];
    v8s qa1 = *(const v8s*)&L[gA + 8];
    v8s qb0 = *(const v8s*)&L[gB];
    v8s qb1 = *(const v8s*)&L[gB + 8];

    // ---- stages 5+6 fused; ld1 pre-scaled -0.5 cancels -2q ----
    v4f a6a[2], a6b[2];
#pragma unroll
    for (int nt = 0; nt < 2; ++nt) {
      v4f s0 = *(const v4f*)&LF[832 + nt * 16 + quad * 4];   // db2 seed
      a6a[nt] = s0; a6b[nt] = s0;
    }
#pragma unroll
    for (int jp = 0; jp < 4; ++jp) {
      v4s hA[2], hB[2];
#pragma unroll
      for (int jj = 0; jj < 2; ++jj) {
        int j = jp * 2 + jj;
        v8s d0 = *(const v8s*)&L[fd1 + j * (16 * SC)];
        v8s d1 = *(const v8s*)&L[fd1 + j * (16 * SC) + 8];
        v4f sd = *(const v4f*)&LF[704 + j * 16 + quad * 4];  // db1 seed
        v4f ha = mfma16(lo4(d0), lo4(qa0), sd);
        ha = mfma16(hi4(d0), hi4(qa0), ha);
        ha = mfma16(lo4(d1), lo4(qa1), ha);
        ha = mfma16(hi4(d1), hi4(qa1), ha);
        v4f hb = mfma16(lo4(d0), lo4(qb0), sd);
        hb = mfma16(hi4(d0), hi4(qb0), hb);
        hb = mfma16(lo4(d1), lo4(qb1), hb);
        hb = mfma16(hi4(d1), hi4(qb1), hb);
        hA[jj] = rlpk(ha); hB[jj] = rlpk(hb);
      }
#pragma unroll
      for (int nt = 0; nt < 2; ++nt) {
        v8s w6 = *(const v8s*)&L[fd2 + nt * (16 * S2) + jp * 8];
        a6a[nt] = mfma16(lo4(w6), hA[0], a6a[nt]);
        a6a[nt] = mfma16(hi4(w6), hA[1], a6a[nt]);
        a6b[nt] = mfma16(lo4(w6), hB[0], a6b[nt]);
        a6b[nt] = mfma16(hi4(w6), hB[1], a6b[nt]);
      }
    }

    // ---- store recon (dwordx4) + loss partials (x regs reused) ----
    {
      float* opa = out + (size_t)(r0 + lm) * IN_DIM;
      float* opb = out + (size_t)(r0 + 16 + lm) * IN_DIM;
      *(float4*)(opa + quad * 4) = (float4){a6a[0][0], a6a[0][1], a6a[0][2], a6a[0][3]};
      *(float4*)(opb + quad * 4) = (float4){a6b[0][0], a6b[0][1], a6b[0][2], a6b[0][3]};
      if (quad < 3) {
        *(float4*)(opa + 16 + quad * 4) = (float4){a6a[1][0], a6a[1][1], a6a[1][2], a6a[1][3]};
        *(float4*)(opb + 16 + quad * 4) = (float4){a6b[1][0], a6b[1][1], a6b[1][2], a6b[1][3]};
      }
      float d0 = a6a[0][0] - xa0.x, d1 = a6a[0][1] - xa0.y,
            d2 = a6a[0][2] - xa0.z, d3 = a6a[0][3] - xa0.w;
      racc += d0 * d0 + d1 * d1 + d2 * d2 + d3 * d3;
      d0 = a6a[1][0] - xa1.x; d1 = a6a[1][1] - xa1.y;
      d2 = a6a[1][2] - xa1.z; d3 = a6a[1][3] - xa1.w;       // quad3: both zero
      racc += d0 * d0 + d1 * d1 + d2 * d2 + d3 * d3;
      d0 = a6b[0][0] - xb0.x; d1 = a6b[0][1] - xb0.y;
      d2 = a6b[0][2] - xb0.z; d3 = a6b[0][3] - xb0.w;
      racc += d0 * d0 + d1 * d1 + d2 * d2 + d3 * d3;
      d0 = a6b[1][0] - xb1.x; d1 = a6b[1][1] - xb1.y;
      d2 = a6b[1][2] - xb1.z; d3 = a6b[1][3] - xb1.w;
      racc += d0 * d0 + d1 * d1 + d2 * d2 + d3 * d3;
    }
  }

  // ---- per-wave butterfly, per-wave partial store (no atomics) ----
#pragma unroll
  for (int off = 1; off < 64; off <<= 1) {
    racc  += __shfl_xor(racc, off, 64);
    vqacc += __shfl_xor(vqacc, off, 64);
  }
  if (lane == 0) {
    size_t w = (size_t)blockIdx.x * WVS + wave;
    partials[w * 2]     = racc;
    partials[w * 2 + 1] = vqacc;
  }
}

// ---------------- finalize: reduce per-wave partials, write scalars ----------------
__global__ __launch_bounds__(256) void vq_fin(const float* __restrict__ partials,
                                              float* __restrict__ out) {
  float r = 0.f, v = 0.f;
  for (int i = threadIdx.x; i < NWAVE; i += 256) {
    r += partials[2 * i];
    v += partials[2 * i + 1];
  }
#pragma unroll
  for (int off = 1; off < 64; off <<= 1) {
    r += __shfl_xor(r, off, 64);
    v += __shfl_xor(v, off, 64);
  }
  __shared__ float s[4][2];
  int w = threadIdx.x >> 6;
  if ((threadIdx.x & 63) == 0) { s[w][0] = r; s[w][1] = v; }
  __syncthreads();
  if (threadIdx.x == 0) {
    float R = s[0][0] + s[1][0] + s[2][0] + s[3][0];
    float V = s[0][1] + s[1][1] + s[2][1] + s[3][1];
    out[7340032] = R * (1.0f / 7340032.0f);          // recon_loss = S / (B*28)
    out[7340033] = V * (1.25f / 16777216.0f);        // vq_loss = 1.25 * S / (B*64)
  }
}

extern "C" void kernel_launch(void* const* d_in, const int* in_sizes, int n_in,
                              void* d_out, int out_size, void* d_ws, size_t ws_size,
                              hipStream_t stream) {
  const float* x   = (const float*)d_in[0];
  const float* ew1 = (const float*)d_in[1];
  const float* eb1 = (const float*)d_in[2];
  const float* ew2 = (const float*)d_in[3];
  const float* eb2 = (const float*)d_in[4];
  const float* cb  = (const float*)d_in[5];
  const float* dw1 = (const float*)d_in[6];
  const float* db1 = (const float*)d_in[7];
  const float* dw2 = (const float*)d_in[8];
  const float* db2 = (const float*)d_in[9];

  char* ws = (char*)d_ws;
  unsigned short* blob = (unsigned short*)(ws + 0);   // 131968 B
  float* partials = (float*)(ws + 132096);            // 32768 B (4096*2 f32)

  float* out = (float*)d_out;

  // allow >64 KB dynamic LDS (gfx950 workgroup max is 160 KB)
  (void)hipFuncSetAttribute((const void*)vq_main,
                            hipFuncAttributeMaxDynamicSharedMemorySize, LDS_BYTES);

  vq_prep<<<255, 256, 0, stream>>>(ew1, eb1, ew2, eb2, cb, dw1, db1, dw2, db2, blob);
  vq_main<<<NBLK, 1024, LDS_BYTES, stream>>>(x, blob, out, partials);
  vq_fin<<<1, 256, 0, stream>>>(partials, out);
}

// Round 3
// 285.387 us; speedup vs baseline: 1.2370x; 1.0399x over previous
//
#include <hip/hip_runtime.h>

#define BATCH   262144
#define IN_DIM  28
#define HID     128
#define LAT     64
#define NCODES  512
#define NBLK    256             // 1024 rows per block (16 waves x 64 rows)
#define WVS     16
#define NWAVE   (NBLK * WVS)    // 4096

// ---- quad-grouped LDS table geometry ----
// Element (row,k) stored at row*S + q'*(K/4) + j*4 + e where k = j*16 + q'*4 + e.
// A lane (lm, quad) reading its mfma16 A-frags for ALL k-chunks of a row reads
// K/4 CONTIGUOUS shorts at row*S + quad*(K/4): pure ds_read_b128, 16B-aligned,
// additive compile-time offsets. Strides 40/72/136 shorts (80/144/272 B) give
// 2-way bank aliasing only (free per m136).
#define S1 40     // lw1  [128][40]  K=32  (k>=28 zero)
#define S2 136    // lw2/ld2 [..][136] K=128
#define SC 72     // lcb/ld1 [..][72]  K=64
#define O_LW1 0
#define O_LW2 5120
#define O_LCB 13824
#define O_LD1 50688
#define O_LD2 59904
#define BLOB_SHORTS 64256
#define BLOB_F32    864
#define BLOB_BYTES  (BLOB_SHORTS * 2 + BLOB_F32 * 4)   // 131968
#define LDS_BYTES   BLOB_BYTES

typedef short v4s __attribute__((ext_vector_type(4)));
typedef short v8s __attribute__((ext_vector_type(8)));
typedef float v4f __attribute__((ext_vector_type(4)));

union u2v4 { unsigned u[2]; v4s s; };

__device__ __forceinline__ unsigned short f2bf(float f) {   // RNE (prep only)
  unsigned u = __float_as_uint(f);
  u += 0x7fffu + ((u >> 16) & 1u);
  return (unsigned short)(u >> 16);
}
// pack two truncated bf16 (hi, lo) in ONE v_perm_b32 (truncation validated r7/r8)
__device__ __forceinline__ unsigned pk(float hi, float lo) {
  return __builtin_amdgcn_perm(__float_as_uint(hi), __float_as_uint(lo), 0x07060302u);
}
// unpack truncated-bf16 lanes of a pk'd u32 back to f32 (for the loss diff)
__device__ __forceinline__ float xf0(unsigned u) { return __uint_as_float(u << 16); }
__device__ __forceinline__ float xf1(unsigned u) { return __uint_as_float(u & 0xFFFF0000u); }

// 16x16x16 bf16 MFMA: k-index = quad*4+e matches C-layout row = quad*4+r,
// so one stage's accumulator (relu+pk'd) IS the next stage's B-fragment.
__device__ __forceinline__ v4f mfma16(v4s a, v4s b, v4f c) {
  return __builtin_amdgcn_mfma_f32_16x16x16bf16_1k(a, b, c, 0, 0, 0);
}
__device__ __forceinline__ v4s lo4(v8s v) { return __builtin_shufflevector(v, v, 0, 1, 2, 3); }
__device__ __forceinline__ v4s hi4(v8s v) { return __builtin_shufflevector(v, v, 4, 5, 6, 7); }

__device__ __forceinline__ v4s rlpk(v4f h) {   // relu + pack to bf16 chunk
  u2v4 c;
  c.u[0] = pk(fmaxf(h[1], 0.f), fmaxf(h[0], 0.f));
  c.u[1] = pk(fmaxf(h[3], 0.f), fmaxf(h[2], 0.f));
  return c.s;
}
// argmin key: dist upper bits | 9-bit code (float order == dist order to 2^-14 rel;
// lowest code wins ties among equal upper bits)
__device__ __forceinline__ float kpack(float d, unsigned code) {
  return __uint_as_float((__float_as_uint(d) & 0xFFFFFE00u) | code);
}

// Blob layout (short offsets), quad-grouped, pad zeroed:
//   lw1 @0      [128 hid][40]   enc_w1^T   (K=32 slot, k>=28 zero)
//   lw2 @5120   [64  lat][136]  enc_w2^T   (K=128)
//   lcb @13824  [512 code][72]  bf16(-2*codebook) (K=64)
//   ld1 @50688  [128 hid][72]   bf16(-0.5*dec_w1^T)  (scale cancels -2q)
//   ld2 @59904  [32  n][136]    dec_w2^T   (rows n>=28 zero)
// f32 @ byte 128512: e2[512], b1[128], b2[64], db1[128], db2[32 pad0]
__global__ __launch_bounds__(256) void vq_prep(
    const float* __restrict__ ew1, const float* __restrict__ eb1,
    const float* __restrict__ ew2, const float* __restrict__ eb2,
    const float* __restrict__ cb,  const float* __restrict__ dw1,
    const float* __restrict__ db1, const float* __restrict__ dw2,
    const float* __restrict__ db2,
    unsigned short* __restrict__ blob) {
  int i = blockIdx.x * 256 + threadIdx.x;
  float* fb = (float*)(blob + BLOB_SHORTS);
  if (i < O_LW2) {                       // lw1 [128][40] K=32 per=8
    int row = i / S1, s = i % S1;
    unsigned short v = 0;
    if (s < 32) {
      int q = s >> 3, r2 = s & 7, j = r2 >> 2, e = r2 & 3;
      int k = j * 16 + q * 4 + e;
      if (k < IN_DIM) v = f2bf(ew1[k * HID + row]);
    }
    blob[i] = v;
  } else if (i < O_LCB) {                // lw2 [64][136] K=128 per=32
    int j2 = i - O_LW2; int row = j2 / S2, s = j2 % S2;
    unsigned short v = 0;
    if (s < 128) {
      int q = s >> 5, r2 = s & 31, j = r2 >> 2, e = r2 & 3;
      int k = j * 16 + q * 4 + e;
      v = f2bf(ew2[k * LAT + row]);
    }
    blob[i] = v;
  } else if (i < O_LD1) {                // lcb [512][72] K=64 per=16, = -2*cb
    int j2 = i - O_LCB; int row = j2 / SC, s = j2 % SC;
    unsigned short v = 0;
    if (s < 64) {
      int q = s >> 4, r2 = s & 15, j = r2 >> 2, e = r2 & 3;
      int k = j * 16 + q * 4 + e;
      v = f2bf(-2.0f * cb[row * LAT + k]);
    }
    blob[i] = v;
  } else if (i < O_LD2) {                // ld1 [128][72] = -0.5*dec_w1^T
    int j2 = i - O_LD1; int row = j2 / SC, s = j2 % SC;
    unsigned short v = 0;
    if (s < 64) {
      int q = s >> 4, r2 = s & 15, j = r2 >> 2, e = r2 & 3;
      int k = j * 16 + q * 4 + e;
      v = f2bf(-0.5f * dw1[k * HID + row]);
    }
    blob[i] = v;
  } else if (i < BLOB_SHORTS) {          // ld2 [32][136]
    int j2 = i - O_LD2; int row = j2 / S2, s = j2 % S2;
    unsigned short v = 0;
    if (s < 128 && row < IN_DIM) {
      int q = s >> 5, r2 = s & 31, j = r2 >> 2, e = r2 & 3;
      int k = j * 16 + q * 4 + e;
      v = f2bf(dw2[k * IN_DIM + row]);
    }
    blob[i] = v;
  } else if (i < BLOB_SHORTS + 512) {    // e2
    int c = i - BLOB_SHORTS;
    float s = 0.f;
    for (int d = 0; d < LAT; ++d) { float v = cb[c * LAT + d]; s += v * v; }
    fb[c] = s;
  } else if (i < BLOB_SHORTS + 640) {
    fb[i - BLOB_SHORTS] = eb1[i - BLOB_SHORTS - 512];
  } else if (i < BLOB_SHORTS + 704) {
    fb[i - BLOB_SHORTS] = eb2[i - BLOB_SHORTS - 640];
  } else if (i < BLOB_SHORTS + 832) {
    fb[i - BLOB_SHORTS] = db1[i - BLOB_SHORTS - 704];
  } else if (i < BLOB_SHORTS + 864) {
    int k = i - BLOB_SHORTS - 832;
    fb[i - BLOB_SHORTS] = (k < IN_DIM) ? db2[k] : 0.f;
  }
}

// ---- phase macros (named scalars only; no ext-vector arrays -> no scratch) ----
#define S1_STEP(J, HA, HB)                                                  \
  {                                                                         \
    v8s w = *(const v8s*)&L[fw1 + (J) * (16 * S1)];                         \
    v4f sd = *(const v4f*)&LF[512 + (J) * 16 + quad * 4];                   \
    v4f ha = mfma16(lo4(w), bxa0.s, sd);                                    \
    ha = mfma16(hi4(w), bxa1.s, ha);                                        \
    v4f hb = mfma16(lo4(w), bxb0.s, sd);                                    \
    hb = mfma16(hi4(w), bxb1.s, hb);                                        \
    HA = rlpk(ha);                                                          \
    HB = rlpk(hb);                                                          \
  }

#define S2_STEP(NT, ZA, ZB, JP, HA0, HA1, HB0, HB1)                         \
  {                                                                         \
    v8s w2 = *(const v8s*)&L[fw2 + (NT) * (16 * S2) + (JP) * 8];            \
    ZA = mfma16(lo4(w2), HA0, ZA);                                          \
    ZA = mfma16(hi4(w2), HA1, ZA);                                          \
    ZB = mfma16(lo4(w2), HB0, ZB);                                          \
    ZB = mfma16(hi4(w2), HB1, ZB);                                          \
  }

#define S12_GROUP(JP)                                                       \
  {                                                                         \
    v4s hA0, hA1, hB0, hB1;                                                 \
    S1_STEP(2 * (JP), hA0, hB0)                                             \
    S1_STEP(2 * (JP) + 1, hA1, hB1)                                         \
    S2_STEP(0, za0, zb0, JP, hA0, hA1, hB0, hB1)                            \
    S2_STEP(1, za1, zb1, JP, hA0, hA1, hB0, hB1)                            \
    S2_STEP(2, za2, zb2, JP, hA0, hA1, hB0, hB1)                            \
    S2_STEP(3, za3, zb3, JP, hA0, hA1, hB0, hB1)                            \
  }

#define S5_STEP(J, HA, HB)                                                  \
  {                                                                         \
    v8s d0 = *(const v8s*)&L[fd1 + (J) * (16 * SC)];                        \
    v8s d1 = *(const v8s*)&L[fd1 + (J) * (16 * SC) + 8];                    \
    v4f sd = *(const v4f*)&LF[704 + (J) * 16 + quad * 4];                   \
    v4f ha = mfma16(lo4(d0), lo4(qa0), sd);                                 \
    ha = mfma16(hi4(d0), hi4(qa0), ha);                                     \
    ha = mfma16(lo4(d1), lo4(qa1), ha);                                     \
    ha = mfma16(hi4(d1), hi4(qa1), ha);                                     \
    v4f hb = mfma16(lo4(d0), lo4(qb0), sd);                                 \
    hb = mfma16(hi4(d0), hi4(qb0), hb);                                     \
    hb = mfma16(lo4(d1), lo4(qb1), hb);                                     \
    hb = mfma16(hi4(d1), hi4(qb1), hb);                                     \
    HA = rlpk(ha);                                                          \
    HB = rlpk(hb);                                                          \
  }

#define S6_STEP(NT, A6A, A6B, JP, HA0, HA1, HB0, HB1)                       \
  {                                                                         \
    v8s w6 = *(const v8s*)&L[fd2 + (NT) * (16 * S2) + (JP) * 8];            \
    A6A = mfma16(lo4(w6), HA0, A6A);                                        \
    A6A = mfma16(hi4(w6), HA1, A6A);                                        \
    A6B = mfma16(lo4(w6), HB0, A6B);                                        \
    A6B = mfma16(hi4(w6), HB1, A6B);                                        \
  }

#define S56_GROUP(JP)                                                       \
  {                                                                         \
    v4s hA0, hA1, hB0, hB1;                                                 \
    S5_STEP(2 * (JP), hA0, hB0)                                             \
    S5_STEP(2 * (JP) + 1, hA1, hB1)                                         \
    S6_STEP(0, a6a0, a6b0, JP, hA0, hA1, hB0, hB1)                          \
    S6_STEP(1, a6a1, a6b1, JP, hA0, hA1, hB0, hB1)                          \
  }

// ---------------- fused main kernel ----------------
// Round-12: r11 structure (2-tile shared fragments, mfma16 register chain,
// quad-grouped b128 tables) + the spill fix its counters demanded:
//  * amdgpu_waves_per_eu(4,4): launch_bounds' 2nd arg is only a MINIMUM -- with
//    dynamic LDS invisible the compiler assumed 2 blocks/CU (8 waves/EU) and
//    capped VGPRs at 64, spilling ~1 KB/thread (550 MB of the 611 MB traffic).
//    Pinning max=4 waves/EU gives the 128-VGPR budget that 16 waves/CU allows.
//  * x kept ONLY as packed bf16 (8 u32 for both tiles, not 16 f32); the loss
//    unpacks them (1 shift/AND per elem). Loss shift <= ~0.004 << 0.02 thr.
//  * all ext-vector arrays -> named scalars; #pragma unroll 1 on the sweep loop.
//    Phase-peak arch-VGPR estimate ~50: fits even a 64+64 VGPR/AGPR split.
__global__ __attribute__((amdgpu_flat_work_group_size(1024, 1024)))
__attribute__((amdgpu_waves_per_eu(4, 4)))
void vq_main(
    const float* __restrict__ x,
    const unsigned short* __restrict__ blob,
    float* __restrict__ out, float* __restrict__ partials) {

  extern __shared__ __align__(16) char smem[];
  const unsigned short* L = (const unsigned short*)smem;
  const float*         LF = (const float*)(smem + BLOB_SHORTS * 2);

  const int tid  = threadIdx.x;
  const int wave = tid >> 6;
  const int lane = tid & 63;
  const int quad = lane >> 4;
  const int lm   = lane & 15;

  // ---- stage tables into LDS (one-time) ----
  {
    const float4* src = (const float4*)blob;
    float4* dst = (float4*)smem;
#pragma unroll
    for (int it = 0; it < 9; ++it) {
      int idx = it * 1024 + tid;
      if (idx < BLOB_BYTES / 16) dst[idx] = src[idx];
    }
  }
  __syncthreads();

  // per-lane fragment bases (short offsets); per-read offsets compile-time imm
  const int fw1 = O_LW1 + lm * S1 + quad * 8;    // + j*(16*S1)
  const int fw2 = O_LW2 + lm * S2 + quad * 32;   // + nt*(16*S2) + jp*8
  const int fcb = O_LCB + lm * SC + quad * 16;   // + ct*(16*SC) (+8)
  const int fd1 = O_LD1 + lm * SC + quad * 16;   // + j*(16*SC) (+8)
  const int fd2 = O_LD2 + lm * S2 + quad * 32;   // + nt*(16*S2) + jp*8

  const int rbase = blockIdx.x * 1024 + wave * 64;
  float racc = 0.f, vqacc = 0.f;

#pragma unroll 1
  for (int sw = 0; sw < 2; ++sw) {
    const int r0 = rbase + sw * 32;

    // ---- x load -> packed bf16 only (f32 temps die immediately) ----
    u2v4 bxa0, bxa1, bxb0, bxb1;
    {
      const float* xpa = x + (size_t)(r0 + lm) * IN_DIM;
      const float* xpb = x + (size_t)(r0 + 16 + lm) * IN_DIM;
      float4 t = *(const float4*)(xpa + quad * 4);
      bxa0.u[0] = pk(t.y, t.x); bxa0.u[1] = pk(t.w, t.z);
      t = *(const float4*)(xpb + quad * 4);
      bxb0.u[0] = pk(t.y, t.x); bxb0.u[1] = pk(t.w, t.z);
      t = (float4){0.f, 0.f, 0.f, 0.f};
      if (quad < 3) t = *(const float4*)(xpa + 16 + quad * 4);
      bxa1.u[0] = pk(t.y, t.x); bxa1.u[1] = pk(t.w, t.z);
      t = (float4){0.f, 0.f, 0.f, 0.f};
      if (quad < 3) t = *(const float4*)(xpb + 16 + quad * 4);
      bxb1.u[0] = pk(t.y, t.x); bxb1.u[1] = pk(t.w, t.z);
    }

    // ---- stages 1+2 fused, both tiles share every weight fragment ----
    v4f za0, za1, za2, za3, zb0, zb1, zb2, zb3;
    {
      v4f s;
      s = *(const v4f*)&LF[640 + 0 * 16 + quad * 4]; za0 = s; zb0 = s;
      s = *(const v4f*)&LF[640 + 1 * 16 + quad * 4]; za1 = s; zb1 = s;
      s = *(const v4f*)&LF[640 + 2 * 16 + quad * 4]; za2 = s; zb2 = s;
      s = *(const v4f*)&LF[640 + 3 * 16 + quad * 4]; za3 = s; zb3 = s;
    }
    S12_GROUP(0)
    S12_GROUP(1)
    S12_GROUP(2)
    S12_GROUP(3)

    // ---- z2 partial (f32 z) + pack z B-frags ----
    float z2a, z2b;
    v4s zfa0, zfa1, zfa2, zfa3, zfb0, zfb1, zfb2, zfb3;
    {
      z2a = za0[0] * za0[0] + za0[1] * za0[1] + za0[2] * za0[2] + za0[3] * za0[3]
          + za1[0] * za1[0] + za1[1] * za1[1] + za1[2] * za1[2] + za1[3] * za1[3]
          + za2[0] * za2[0] + za2[1] * za2[1] + za2[2] * za2[2] + za2[3] * za2[3]
          + za3[0] * za3[0] + za3[1] * za3[1] + za3[2] * za3[2] + za3[3] * za3[3];
      z2b = zb0[0] * zb0[0] + zb0[1] * zb0[1] + zb0[2] * zb0[2] + zb0[3] * zb0[3]
          + zb1[0] * zb1[0] + zb1[1] * zb1[1] + zb1[2] * zb1[2] + zb1[3] * zb1[3]
          + zb2[0] * zb2[0] + zb2[1] * zb2[1] + zb2[2] * zb2[2] + zb2[3] * zb2[3]
          + zb3[0] * zb3[0] + zb3[1] * zb3[1] + zb3[2] * zb3[2] + zb3[3] * zb3[3];
      u2v4 p;
      p.u[0] = pk(za0[1], za0[0]); p.u[1] = pk(za0[3], za0[2]); zfa0 = p.s;
      p.u[0] = pk(za1[1], za1[0]); p.u[1] = pk(za1[3], za1[2]); zfa1 = p.s;
      p.u[0] = pk(za2[1], za2[0]); p.u[1] = pk(za2[3], za2[2]); zfa2 = p.s;
      p.u[0] = pk(za3[1], za3[0]); p.u[1] = pk(za3[3], za3[2]); zfa3 = p.s;
      p.u[0] = pk(zb0[1], zb0[0]); p.u[1] = pk(zb0[3], zb0[2]); zfb0 = p.s;
      p.u[0] = pk(zb1[1], zb1[0]); p.u[1] = pk(zb1[3], zb1[2]); zfb1 = p.s;
      p.u[0] = pk(zb2[1], zb2[0]); p.u[1] = pk(zb2[3], zb2[2]); zfb2 = p.s;
      p.u[0] = pk(zb3[1], zb3[0]); p.u[1] = pk(zb3[3], zb3[2]); zfb3 = p.s;
    }

    // ---- argmin: dist^T = e2 + (-2e)·z; cb fragments shared by both tiles ----
    float bkA = __uint_as_float(0x7f7fffffu);
    float bkB = bkA;
#pragma unroll 2
    for (int ct = 0; ct < 32; ++ct) {
      v8s c0 = *(const v8s*)&L[fcb + ct * (16 * SC)];        // chunks 0,1
      v8s c1 = *(const v8s*)&L[fcb + ct * (16 * SC) + 8];    // chunks 2,3
      v4f sd = *(const v4f*)&LF[ct * 16 + quad * 4];         // e2 seed
      v4f dA = mfma16(lo4(c0), zfa0, sd);
      dA = mfma16(hi4(c0), zfa1, dA);
      dA = mfma16(lo4(c1), zfa2, dA);
      dA = mfma16(hi4(c1), zfa3, dA);
      v4f dB = mfma16(lo4(c0), zfb0, sd);
      dB = mfma16(hi4(c0), zfb1, dB);
      dB = mfma16(lo4(c1), zfb2, dB);
      dB = mfma16(hi4(c1), zfb3, dB);
      unsigned cbase = (unsigned)(ct * 16 + quad * 4);
      bkA = fminf(bkA, fminf(fminf(kpack(dA[0], cbase), kpack(dA[1], cbase + 1)),
                             fminf(kpack(dA[2], cbase + 2), kpack(dA[3], cbase + 3))));
      bkB = fminf(bkB, fminf(fminf(kpack(dB[0], cbase), kpack(dB[1], cbase + 1)),
                             fminf(kpack(dB[2], cbase + 2), kpack(dB[3], cbase + 3))));
    }

    // ---- cross-quad argmin + z2 reduce ----
#pragma unroll
    for (int off = 16; off < 64; off <<= 1) {
      bkA = fminf(bkA, __shfl_xor(bkA, off, 64));
      bkB = fminf(bkB, __shfl_xor(bkB, off, 64));
      z2a += __shfl_xor(z2a, off, 64);
      z2b += __shfl_xor(z2b, off, 64);
    }
    unsigned ka = __float_as_uint(bkA), kb = __float_as_uint(bkB);
    int codeA = (int)(ka & 511u), codeB = (int)(kb & 511u);
    if (quad == 0)
      vqacc += z2a + __uint_as_float(ka & 0xFFFFFE00u)
             + z2b + __uint_as_float(kb & 0xFFFFFE00u);      // ||z-q||^2

    // ---- gather -2q (2x b128 each tile, quad-broadcast) ----
    const int gA = O_LCB + codeA * SC + quad * 16;
    const int gB = O_LCB + codeB * SC + quad * 16;
    v8s qa0 = *(const v8s*)&L[gA];
    v8s qa1 = *(const v8s*)&L[gA + 8];
    v8s qb0 = *(const v8s*)&L[gB];
    v8s qb1 = *(const v8s*)&L[gB + 8];

    // ---- stages 5+6 fused; ld1 pre-scaled -0.5 cancels -2q ----
    v4f a6a0, a6a1, a6b0, a6b1;
    {
      v4f s;
      s = *(const v4f*)&LF[832 + quad * 4]; a6a0 = s; a6b0 = s;
      s = *(const v4f*)&LF[848 + quad * 4]; a6a1 = s; a6b1 = s;
    }
    S56_GROUP(0)
    S56_GROUP(1)
    S56_GROUP(2)
    S56_GROUP(3)

    // ---- store recon (dwordx4) + loss partials (x from bf16 packs) ----
    {
      float* opa = out + (size_t)(r0 + lm) * IN_DIM;
      float* opb = out + (size_t)(r0 + 16 + lm) * IN_DIM;
      *(float4*)(opa + quad * 4) = (float4){a6a0[0], a6a0[1], a6a0[2], a6a0[3]};
      *(float4*)(opb + quad * 4) = (float4){a6b0[0], a6b0[1], a6b0[2], a6b0[3]};
      if (quad < 3) {
        *(float4*)(opa + 16 + quad * 4) = (float4){a6a1[0], a6a1[1], a6a1[2], a6a1[3]};
        *(float4*)(opb + 16 + quad * 4) = (float4){a6b1[0], a6b1[1], a6b1[2], a6b1[3]};
      }
      float d;
      d = a6a0[0] - xf0(bxa0.u[0]); racc += d * d;
      d = a6a0[1] - xf1(bxa0.u[0]); racc += d * d;
      d = a6a0[2] - xf0(bxa0.u[1]); racc += d * d;
      d = a6a0[3] - xf1(bxa0.u[1]); racc += d * d;
      d = a6a1[0] - xf0(bxa1.u[0]); racc += d * d;    // quad3: both zero
      d = a6a1[1] - xf1(bxa1.u[0]); racc += d * d;
      d = a6a1[2] - xf0(bxa1.u[1]); racc += d * d;
      d = a6a1[3] - xf1(bxa1.u[1]); racc += d * d;
      d = a6b0[0] - xf0(bxb0.u[0]); racc += d * d;
      d = a6b0[1] - xf1(bxb0.u[0]); racc += d * d;
      d = a6b0[2] - xf0(bxb0.u[1]); racc += d * d;
      d = a6b0[3] - xf1(bxb0.u[1]); racc += d * d;
      d = a6b1[0] - xf0(bxb1.u[0]); racc += d * d;
      d = a6b1[1] - xf1(bxb1.u[0]); racc += d * d;
      d = a6b1[2] - xf0(bxb1.u[1]); racc += d * d;
      d = a6b1[3] - xf1(bxb1.u[1]); racc += d * d;
    }
  }

  // ---- per-wave butterfly, per-wave partial store (no atomics) ----
#pragma unroll
  for (int off = 1; off < 64; off <<= 1) {
    racc  += __shfl_xor(racc, off, 64);
    vqacc += __shfl_xor(vqacc, off, 64);
  }
  if (lane == 0) {
    size_t w = (size_t)blockIdx.x * WVS + wave;
    partials[w * 2]     = racc;
    partials[w * 2 + 1] = vqacc;
  }
}

// ---------------- finalize: reduce per-wave partials, write scalars ----------------
__global__ __launch_bounds__(256) void vq_fin(const float* __restrict__ partials,
                                              float* __restrict__ out) {
  float r = 0.f, v = 0.f;
  for (int i = threadIdx.x; i < NWAVE; i += 256) {
    r += partials[2 * i];
    v += partials[2 * i + 1];
  }
#pragma unroll
  for (int off = 1; off < 64; off <<= 1) {
    r += __shfl_xor(r, off, 64);
    v += __shfl_xor(v, off, 64);
  }
  __shared__ float s[4][2];
  int w = threadIdx.x >> 6;
  if ((threadIdx.x & 63) == 0) { s[w][0] = r; s[w][1] = v; }
  __syncthreads();
  if (threadIdx.x == 0) {
    float R = s[0][0] + s[1][0] + s[2][0] + s[3][0];
    float V = s[0][1] + s[1][1] + s[2][1] + s[3][1];
    out[7340032] = R * (1.0f / 7340032.0f);          // recon_loss = S / (B*28)
    out[7340033] = V * (1.25f / 16777216.0f);        // vq_loss = 1.25 * S / (B*64)
  }
}

extern "C" void kernel_launch(void* const* d_in, const int* in_sizes, int n_in,
                              void* d_out, int out_size, void* d_ws, size_t ws_size,
                              hipStream_t stream) {
  const float* x   = (const float*)d_in[0];
  const float* ew1 = (const float*)d_in[1];
  const float* eb1 = (const float*)d_in[2];
  const float* ew2 = (const float*)d_in[3];
  const float* eb2 = (const float*)d_in[4];
  const float* cb  = (const float*)d_in[5];
  const float* dw1 = (const float*)d_in[6];
  const float* db1 = (const float*)d_in[7];
  const float* dw2 = (const float*)d_in[8];
  const float* db2 = (const float*)d_in[9];

  char* ws = (char*)d_ws;
  unsigned short* blob = (unsigned short*)(ws + 0);   // 131968 B
  float* partials = (float*)(ws + 132096);            // 32768 B (4096*2 f32)

  float* out = (float*)d_out;

  // allow >64 KB dynamic LDS (gfx950 workgroup max is 160 KB)
  (void)hipFuncSetAttribute((const void*)vq_main,
                            hipFuncAttributeMaxDynamicSharedMemorySize, LDS_BYTES);

  vq_prep<<<255, 256, 0, stream>>>(ew1, eb1, ew2, eb2, cb, dw1, db1, dw2, db2, blob);
  vq_main<<<NBLK, 1024, LDS_BYTES, stream>>>(x, blob, out, partials);
  vq_fin<<<1, 256, 0, stream>>>(partials, out);
}

// Round 4
// 138.225 us; speedup vs baseline: 2.5539x; 2.0647x over previous
//
#include <hip/hip_runtime.h>

#define BATCH   262144
#define IN_DIM  28
#define HID     128
#define LAT     64
#define NCODES  512
#define NBLK    256             // 1024 rows per block (16 waves x 64 rows)
#define WVS     16
#define NWAVE   (NBLK * WVS)    // 4096

// ---- quad-grouped LDS table geometry ----
// Element (row,k) stored at row*S + q'*(K/4) + j*4 + e where k = j*16 + q'*4 + e.
// A lane (lm, quad) reading its mfma16 A-frags reads K/4 CONTIGUOUS shorts at
// row*S + quad*(K/4): pure ds_read_b128, 16B-aligned. Strides 40/72/136 shorts
// (80/144/272 B) give 2-way bank aliasing only (free per m136).
#define S1 40     // lw1  [128][40]  K=32  (k>=28 zero)
#define S2 136    // lw2/ld2 [..][136] K=128
#define SC 72     // lcb/ld1 [..][72]  K=64
#define O_LW1 0
#define O_LW2 5120
#define O_LCB 13824
#define O_LD1 50688
#define O_LD2 59904
#define BLOB_SHORTS 64256
#define BLOB_F32    864
#define BLOB_BYTES  (BLOB_SHORTS * 2 + BLOB_F32 * 4)   // 131968
#define LDS_BYTES   BLOB_BYTES

typedef short v4s __attribute__((ext_vector_type(4)));
typedef short v8s __attribute__((ext_vector_type(8)));
typedef float v4f __attribute__((ext_vector_type(4)));

union u2v4 { unsigned u[2]; v4s s; };

__device__ __forceinline__ unsigned short f2bf(float f) {   // RNE (prep only)
  unsigned u = __float_as_uint(f);
  u += 0x7fffu + ((u >> 16) & 1u);
  return (unsigned short)(u >> 16);
}
// pack two truncated bf16 (hi, lo) in ONE v_perm_b32 (truncation validated r7/r8)
__device__ __forceinline__ unsigned pk(float hi, float lo) {
  return __builtin_amdgcn_perm(__float_as_uint(hi), __float_as_uint(lo), 0x07060302u);
}
// unpack truncated-bf16 lanes of a pk'd u32 back to f32 (for the loss diff)
__device__ __forceinline__ float xf0(unsigned u) { return __uint_as_float(u << 16); }
__device__ __forceinline__ float xf1(unsigned u) { return __uint_as_float(u & 0xFFFF0000u); }

// 16x16x16 bf16 MFMA: k-index = quad*4+e matches C-layout row = quad*4+r,
// so one stage's accumulator (relu+pk'd) IS the next stage's B-fragment.
__device__ __forceinline__ v4f mfma16(v4s a, v4s b, v4f c) {
  return __builtin_amdgcn_mfma_f32_16x16x16bf16_1k(a, b, c, 0, 0, 0);
}
__device__ __forceinline__ v4s lo4(v8s v) { return __builtin_shufflevector(v, v, 0, 1, 2, 3); }
__device__ __forceinline__ v4s hi4(v8s v) { return __builtin_shufflevector(v, v, 4, 5, 6, 7); }

__device__ __forceinline__ v4s rlpk(v4f h) {   // relu + pack to bf16 chunk
  u2v4 c;
  c.u[0] = pk(fmaxf(h[1], 0.f), fmaxf(h[0], 0.f));
  c.u[1] = pk(fmaxf(h[3], 0.f), fmaxf(h[2], 0.f));
  return c.s;
}
__device__ __forceinline__ v4s zpk(v4f z) {    // pack to bf16 chunk
  u2v4 c; c.u[0] = pk(z[1], z[0]); c.u[1] = pk(z[3], z[2]); return c.s;
}
__device__ __forceinline__ v4s mkv(unsigned a, unsigned b) {
  u2v4 c; c.u[0] = a; c.u[1] = b; return c.s;
}
// argmin key: dist upper bits | 9-bit code (float order == dist order to 2^-14 rel;
// lowest code wins ties among equal upper bits)
__device__ __forceinline__ float kpack(float d, unsigned code) {
  return __uint_as_float((__float_as_uint(d) & 0xFFFFFE00u) | code);
}

// Blob layout (short offsets), quad-grouped, pad zeroed:
//   lw1 @0      [128 hid][40]   enc_w1^T   (K=32 slot, k>=28 zero)
//   lw2 @5120   [64  lat][136]  enc_w2^T   (K=128)
//   lcb @13824  [512 code][72]  bf16(-2*codebook) (K=64)
//   ld1 @50688  [128 hid][72]   bf16(-0.5*dec_w1^T)  (scale cancels -2q)
//   ld2 @59904  [32  n][136]    dec_w2^T   (rows n>=28 zero)
// f32 @ byte 128512: e2[512], b1[128], b2[64], db1[128], db2[32 pad0]
__global__ __launch_bounds__(256) void vq_prep(
    const float* __restrict__ ew1, const float* __restrict__ eb1,
    const float* __restrict__ ew2, const float* __restrict__ eb2,
    const float* __restrict__ cb,  const float* __restrict__ dw1,
    const float* __restrict__ db1, const float* __restrict__ dw2,
    const float* __restrict__ db2,
    unsigned short* __restrict__ blob) {
  int i = blockIdx.x * 256 + threadIdx.x;
  float* fb = (float*)(blob + BLOB_SHORTS);
  if (i < O_LW2) {                       // lw1 [128][40] K=32 per=8
    int row = i / S1, s = i % S1;
    unsigned short v = 0;
    if (s < 32) {
      int q = s >> 3, r2 = s & 7, j = r2 >> 2, e = r2 & 3;
      int k = j * 16 + q * 4 + e;
      if (k < IN_DIM) v = f2bf(ew1[k * HID + row]);
    }
    blob[i] = v;
  } else if (i < O_LCB) {                // lw2 [64][136] K=128 per=32
    int j2 = i - O_LW2; int row = j2 / S2, s = j2 % S2;
    unsigned short v = 0;
    if (s < 128) {
      int q = s >> 5, r2 = s & 31, j = r2 >> 2, e = r2 & 3;
      int k = j * 16 + q * 4 + e;
      v = f2bf(ew2[k * LAT + row]);
    }
    blob[i] = v;
  } else if (i < O_LD1) {                // lcb [512][72] K=64 per=16, = -2*cb
    int j2 = i - O_LCB; int row = j2 / SC, s = j2 % SC;
    unsigned short v = 0;
    if (s < 64) {
      int q = s >> 4, r2 = s & 15, j = r2 >> 2, e = r2 & 3;
      int k = j * 16 + q * 4 + e;
      v = f2bf(-2.0f * cb[row * LAT + k]);
    }
    blob[i] = v;
  } else if (i < O_LD2) {                // ld1 [128][72] = -0.5*dec_w1^T
    int j2 = i - O_LD1; int row = j2 / SC, s = j2 % SC;
    unsigned short v = 0;
    if (s < 64) {
      int q = s >> 4, r2 = s & 15, j = r2 >> 2, e = r2 & 3;
      int k = j * 16 + q * 4 + e;
      v = f2bf(-0.5f * dw1[k * HID + row]);
    }
    blob[i] = v;
  } else if (i < BLOB_SHORTS) {          // ld2 [32][136]
    int j2 = i - O_LD2; int row = j2 / S2, s = j2 % S2;
    unsigned short v = 0;
    if (s < 128 && row < IN_DIM) {
      int q = s >> 5, r2 = s & 31, j = r2 >> 2, e = r2 & 3;
      int k = j * 16 + q * 4 + e;
      v = f2bf(dw2[k * IN_DIM + row]);
    }
    blob[i] = v;
  } else if (i < BLOB_SHORTS + 512) {    // e2
    int c = i - BLOB_SHORTS;
    float s = 0.f;
    for (int d = 0; d < LAT; ++d) { float v = cb[c * LAT + d]; s += v * v; }
    fb[c] = s;
  } else if (i < BLOB_SHORTS + 640) {
    fb[i - BLOB_SHORTS] = eb1[i - BLOB_SHORTS - 512];
  } else if (i < BLOB_SHORTS + 704) {
    fb[i - BLOB_SHORTS] = eb2[i - BLOB_SHORTS - 640];
  } else if (i < BLOB_SHORTS + 832) {
    fb[i - BLOB_SHORTS] = db1[i - BLOB_SHORTS - 704];
  } else if (i < BLOB_SHORTS + 864) {
    int k = i - BLOB_SHORTS - 832;
    fb[i - BLOB_SHORTS] = (k < IN_DIM) ? db2[k] : 0.f;
  }
}

// ---- per-tile stage 1+2: x -> h -> z, one tile's accumulators live at a time.
// jp-loop is #pragma unroll 1: the back-edge caps scheduler load-hoisting, so at
// most one group's fragments (~6 v8s) are in flight -> no regalloc blowup.
__device__ __forceinline__ void s12_tile(
    const unsigned short* __restrict__ L, const float* __restrict__ LF,
    int lm, int quad, v4s bxlo, v4s bxhi,
    v4s& zf0, v4s& zf1, v4s& zf2, v4s& zf3, float& z2) {
  const int fw1 = O_LW1 + lm * S1 + quad * 8;
  const int fw2 = O_LW2 + lm * S2 + quad * 32;
  v4f za[4];
#pragma unroll
  for (int nt = 0; nt < 4; ++nt)
    za[nt] = *(const v4f*)&LF[640 + nt * 16 + quad * 4];     // b2 seed
#pragma unroll 1
  for (int jp = 0; jp < 4; ++jp) {
    v4s h0, h1;
    {
      v8s w = *(const v8s*)&L[fw1 + (2 * jp) * (16 * S1)];
      v4f sd = *(const v4f*)&LF[512 + (2 * jp) * 16 + quad * 4];   // b1 seed
      v4f h = mfma16(lo4(w), bxlo, sd);
      h = mfma16(hi4(w), bxhi, h);
      h0 = rlpk(h);
    }
    {
      v8s w = *(const v8s*)&L[fw1 + (2 * jp + 1) * (16 * S1)];
      v4f sd = *(const v4f*)&LF[512 + (2 * jp + 1) * 16 + quad * 4];
      v4f h = mfma16(lo4(w), bxlo, sd);
      h = mfma16(hi4(w), bxhi, h);
      h1 = rlpk(h);
    }
#pragma unroll
    for (int nt = 0; nt < 4; ++nt) {
      v8s w2 = *(const v8s*)&L[fw2 + nt * (16 * S2) + jp * 8];
      za[nt] = mfma16(lo4(w2), h0, za[nt]);
      za[nt] = mfma16(hi4(w2), h1, za[nt]);
    }
  }
  z2 = za[0][0] * za[0][0] + za[0][1] * za[0][1] + za[0][2] * za[0][2] + za[0][3] * za[0][3]
     + za[1][0] * za[1][0] + za[1][1] * za[1][1] + za[1][2] * za[1][2] + za[1][3] * za[1][3]
     + za[2][0] * za[2][0] + za[2][1] * za[2][1] + za[2][2] * za[2][2] + za[2][3] * za[2][3]
     + za[3][0] * za[3][0] + za[3][1] * za[3][1] + za[3][2] * za[3][2] + za[3][3] * za[3][3];
  zf0 = zpk(za[0]); zf1 = zpk(za[1]); zf2 = zpk(za[2]); zf3 = zpk(za[3]);
}

// ---- per-tile stage 5+6: q -> hd -> recon (+store +loss) ----
__device__ __forceinline__ void s56_tile(
    const unsigned short* __restrict__ L, const float* __restrict__ LF,
    int lm, int quad, int code,
    unsigned bxu0, unsigned bxu1, unsigned bxu2, unsigned bxu3,
    float* __restrict__ orow, float& racc) {
  const int fd1 = O_LD1 + lm * SC + quad * 16;
  const int fd2 = O_LD2 + lm * S2 + quad * 32;
  const int g = O_LCB + code * SC + quad * 16;   // -2q, quad-grouped row
  v8s q0 = *(const v8s*)&L[g];
  v8s q1 = *(const v8s*)&L[g + 8];
  v4f a6[2];
  a6[0] = *(const v4f*)&LF[832 + quad * 4];      // db2 seed
  a6[1] = *(const v4f*)&LF[848 + quad * 4];
#pragma unroll 1
  for (int jp = 0; jp < 4; ++jp) {
    v4s h0, h1;
    {
      int j = 2 * jp;
      v8s d0 = *(const v8s*)&L[fd1 + j * (16 * SC)];
      v8s d1 = *(const v8s*)&L[fd1 + j * (16 * SC) + 8];
      v4f sd = *(const v4f*)&LF[704 + j * 16 + quad * 4];    // db1 seed
      v4f h = mfma16(lo4(d0), lo4(q0), sd);
      h = mfma16(hi4(d0), hi4(q0), h);
      h = mfma16(lo4(d1), lo4(q1), h);
      h = mfma16(hi4(d1), hi4(q1), h);
      h0 = rlpk(h);
    }
    {
      int j = 2 * jp + 1;
      v8s d0 = *(const v8s*)&L[fd1 + j * (16 * SC)];
      v8s d1 = *(const v8s*)&L[fd1 + j * (16 * SC) + 8];
      v4f sd = *(const v4f*)&LF[704 + j * 16 + quad * 4];
      v4f h = mfma16(lo4(d0), lo4(q0), sd);
      h = mfma16(hi4(d0), hi4(q0), h);
      h = mfma16(lo4(d1), lo4(q1), h);
      h = mfma16(hi4(d1), hi4(q1), h);
      h1 = rlpk(h);
    }
#pragma unroll
    for (int nt = 0; nt < 2; ++nt) {
      v8s w6 = *(const v8s*)&L[fd2 + nt * (16 * S2) + jp * 8];
      a6[nt] = mfma16(lo4(w6), h0, a6[nt]);
      a6[nt] = mfma16(hi4(w6), h1, a6[nt]);
    }
  }
  *(float4*)(orow + quad * 4) = (float4){a6[0][0], a6[0][1], a6[0][2], a6[0][3]};
  if (quad < 3)
    *(float4*)(orow + 16 + quad * 4) = (float4){a6[1][0], a6[1][1], a6[1][2], a6[1][3]};
  float d;
  d = a6[0][0] - xf0(bxu0); racc += d * d;
  d = a6[0][1] - xf1(bxu0); racc += d * d;
  d = a6[0][2] - xf0(bxu1); racc += d * d;
  d = a6[0][3] - xf1(bxu1); racc += d * d;
  d = a6[1][0] - xf0(bxu2); racc += d * d;   // quad3: a6[1]==0 and x==0
  d = a6[1][1] - xf1(bxu2); racc += d * d;
  d = a6[1][2] - xf0(bxu3); racc += d * d;
  d = a6[1][3] - xf1(bxu3); racc += d * d;
}

// ---------------- fused main kernel ----------------
// Round-13: demand-side spill fix. r11/r12's fully-unrolled 2-tile macro chains
// let the scheduler hoist ~20 v8s table fragments (~160 VGPRs in flight) ->
// ~250 dwords/thread scratch regardless of budget attributes. This round caps
// DEMAND structurally: runtime-jp `#pragma unroll 1` loops inside each stage,
// tiles A/B sequential through S12 and S56 (accumulators 16 regs at a time),
// sched_barrier(0) between phases so inlined calls can't re-merge. Argmin (the
// dominant LDS phase) keeps 2-tile fragment sharing. Phase-peak ~60 VGPRs:
// fits even a hard 64-arch-VGPR allocation.
__global__ __attribute__((amdgpu_flat_work_group_size(1024, 1024)))
__attribute__((amdgpu_waves_per_eu(4, 4)))
void vq_main(
    const float* __restrict__ x,
    const unsigned short* __restrict__ blob,
    float* __restrict__ out, float* __restrict__ partials) {

  extern __shared__ __align__(16) char smem[];
  const unsigned short* L = (const unsigned short*)smem;
  const float*         LF = (const float*)(smem + BLOB_SHORTS * 2);

  const int tid  = threadIdx.x;
  const int wave = tid >> 6;
  const int lane = tid & 63;
  const int quad = lane >> 4;
  const int lm   = lane & 15;

  // ---- stage tables into LDS (one-time) ----
  {
    const float4* src = (const float4*)blob;
    float4* dst = (float4*)smem;
#pragma unroll
    for (int it = 0; it < 9; ++it) {
      int idx = it * 1024 + tid;
      if (idx < BLOB_BYTES / 16) dst[idx] = src[idx];
    }
  }
  __syncthreads();

  const int rbase = blockIdx.x * 1024 + wave * 64;
  float racc = 0.f, vqacc = 0.f;

#pragma unroll 1
  for (int sw = 0; sw < 2; ++sw) {
    const int r0 = rbase + sw * 32;

    // ---- x load -> packed bf16 only (f32 temps die immediately) ----
    unsigned xa0, xa1, xa2, xa3, xb0, xb1, xb2, xb3;
    {
      const float* xpa = x + (size_t)(r0 + lm) * IN_DIM;
      const float* xpb = x + (size_t)(r0 + 16 + lm) * IN_DIM;
      float4 t = *(const float4*)(xpa + quad * 4);
      xa0 = pk(t.y, t.x); xa1 = pk(t.w, t.z);
      t = (quad < 3) ? *(const float4*)(xpa + 16 + quad * 4) : (float4){0.f, 0.f, 0.f, 0.f};
      xa2 = pk(t.y, t.x); xa3 = pk(t.w, t.z);
      t = *(const float4*)(xpb + quad * 4);
      xb0 = pk(t.y, t.x); xb1 = pk(t.w, t.z);
      t = (quad < 3) ? *(const float4*)(xpb + 16 + quad * 4) : (float4){0.f, 0.f, 0.f, 0.f};
      xb2 = pk(t.y, t.x); xb3 = pk(t.w, t.z);
    }

    // ---- stages 1+2, tile A then tile B (sequential: 16-reg accumulators) ----
    v4s zfa0, zfa1, zfa2, zfa3, zfb0, zfb1, zfb2, zfb3;
    float z2a, z2b;
    s12_tile(L, LF, lm, quad, mkv(xa0, xa1), mkv(xa2, xa3), zfa0, zfa1, zfa2, zfa3, z2a);
    __builtin_amdgcn_sched_barrier(0);
    s12_tile(L, LF, lm, quad, mkv(xb0, xb1), mkv(xb2, xb3), zfb0, zfb1, zfb2, zfb3, z2b);
    __builtin_amdgcn_sched_barrier(0);

    // ---- argmin: dist^T = e2 + (-2e)·z; cb fragments SHARED by both tiles ----
    const int fcb = O_LCB + lm * SC + quad * 16;
    float bkA = __uint_as_float(0x7f7fffffu);
    float bkB = bkA;
#pragma unroll 2
    for (int ct = 0; ct < 32; ++ct) {
      v8s c0 = *(const v8s*)&L[fcb + ct * (16 * SC)];        // chunks 0,1
      v8s c1 = *(const v8s*)&L[fcb + ct * (16 * SC) + 8];    // chunks 2,3
      v4f sd = *(const v4f*)&LF[ct * 16 + quad * 4];         // e2 seed
      v4f dA = mfma16(lo4(c0), zfa0, sd);
      dA = mfma16(hi4(c0), zfa1, dA);
      dA = mfma16(lo4(c1), zfa2, dA);
      dA = mfma16(hi4(c1), zfa3, dA);
      v4f dB = mfma16(lo4(c0), zfb0, sd);
      dB = mfma16(hi4(c0), zfb1, dB);
      dB = mfma16(lo4(c1), zfb2, dB);
      dB = mfma16(hi4(c1), zfb3, dB);
      unsigned cbase = (unsigned)(ct * 16 + quad * 4);
      bkA = fminf(bkA, fminf(fminf(kpack(dA[0], cbase), kpack(dA[1], cbase + 1)),
                             fminf(kpack(dA[2], cbase + 2), kpack(dA[3], cbase + 3))));
      bkB = fminf(bkB, fminf(fminf(kpack(dB[0], cbase), kpack(dB[1], cbase + 1)),
                             fminf(kpack(dB[2], cbase + 2), kpack(dB[3], cbase + 3))));
    }

    // ---- cross-quad argmin + z2 reduce ----
#pragma unroll
    for (int off = 16; off < 64; off <<= 1) {
      bkA = fminf(bkA, __shfl_xor(bkA, off, 64));
      bkB = fminf(bkB, __shfl_xor(bkB, off, 64));
      z2a += __shfl_xor(z2a, off, 64);
      z2b += __shfl_xor(z2b, off, 64);
    }
    unsigned ka = __float_as_uint(bkA), kb = __float_as_uint(bkB);
    int codeA = (int)(ka & 511u), codeB = (int)(kb & 511u);
    if (quad == 0)
      vqacc += z2a + __uint_as_float(ka & 0xFFFFFE00u)
             + z2b + __uint_as_float(kb & 0xFFFFFE00u);      // ||z-q||^2
    __builtin_amdgcn_sched_barrier(0);

    // ---- stages 5+6 + store + loss, tile A then tile B ----
    s56_tile(L, LF, lm, quad, codeA, xa0, xa1, xa2, xa3,
             out + (size_t)(r0 + lm) * IN_DIM, racc);
    __builtin_amdgcn_sched_barrier(0);
    s56_tile(L, LF, lm, quad, codeB, xb0, xb1, xb2, xb3,
             out + (size_t)(r0 + 16 + lm) * IN_DIM, racc);
  }

  // ---- per-wave butterfly, per-wave partial store (no atomics) ----
#pragma unroll
  for (int off = 1; off < 64; off <<= 1) {
    racc  += __shfl_xor(racc, off, 64);
    vqacc += __shfl_xor(vqacc, off, 64);
  }
  if (lane == 0) {
    size_t w = (size_t)blockIdx.x * WVS + wave;
    partials[w * 2]     = racc;
    partials[w * 2 + 1] = vqacc;
  }
}

// ---------------- finalize: reduce per-wave partials, write scalars ----------------
__global__ __launch_bounds__(256) void vq_fin(const float* __restrict__ partials,
                                              float* __restrict__ out) {
  float r = 0.f, v = 0.f;
  for (int i = threadIdx.x; i < NWAVE; i += 256) {
    r += partials[2 * i];
    v += partials[2 * i + 1];
  }
#pragma unroll
  for (int off = 1; off < 64; off <<= 1) {
    r += __shfl_xor(r, off, 64);
    v += __shfl_xor(v, off, 64);
  }
  __shared__ float s[4][2];
  int w = threadIdx.x >> 6;
  if ((threadIdx.x & 63) == 0) { s[w][0] = r; s[w][1] = v; }
  __syncthreads();
  if (threadIdx.x == 0) {
    float R = s[0][0] + s[1][0] + s[2][0] + s[3][0];
    float V = s[0][1] + s[1][1] + s[2][1] + s[3][1];
    out[7340032] = R * (1.0f / 7340032.0f);          // recon_loss = S / (B*28)
    out[7340033] = V * (1.25f / 16777216.0f);        // vq_loss = 1.25 * S / (B*64)
  }
}

extern "C" void kernel_launch(void* const* d_in, const int* in_sizes, int n_in,
                              void* d_out, int out_size, void* d_ws, size_t ws_size,
                              hipStream_t stream) {
  const float* x   = (const float*)d_in[0];
  const float* ew1 = (const float*)d_in[1];
  const float* eb1 = (const float*)d_in[2];
  const float* ew2 = (const float*)d_in[3];
  const float* eb2 = (const float*)d_in[4];
  const float* cb  = (const float*)d_in[5];
  const float* dw1 = (const float*)d_in[6];
  const float* db1 = (const float*)d_in[7];
  const float* dw2 = (const float*)d_in[8];
  const float* db2 = (const float*)d_in[9];

  char* ws = (char*)d_ws;
  unsigned short* blob = (unsigned short*)(ws + 0);   // 131968 B
  float* partials = (float*)(ws + 132096);            // 32768 B (4096*2 f32)

  float* out = (float*)d_out;

  // allow >64 KB dynamic LDS (gfx950 workgroup max is 160 KB)
  (void)hipFuncSetAttribute((const void*)vq_main,
                            hipFuncAttributeMaxDynamicSharedMemorySize, LDS_BYTES);

  vq_prep<<<255, 256, 0, stream>>>(ew1, eb1, ew2, eb2, cb, dw1, db1, dw2, db2, blob);
  vq_main<<<NBLK, 1024, LDS_BYTES, stream>>>(x, blob, out, partials);
  vq_fin<<<1, 256, 0, stream>>>(partials, out);
}

// Round 5
// 134.465 us; speedup vs baseline: 2.6253x; 1.0280x over previous
//
#include <hip/hip_runtime.h>

#define BATCH   262144
#define IN_DIM  28
#define HID     128
#define LAT     64
#define NCODES  512
#define NBLK    256             // 1024 rows per block (16 waves x 64 rows)
#define WVS     16
#define NWAVE   (NBLK * WVS)    // 4096

// ---- quad-grouped LDS table geometry ----
// Element (row,k) stored at row*S + q'*(K/4) + j*4 + e where k = j*16 + q'*4 + e.
// A lane (lm, quad) reading its mfma16 A-frags reads K/4 CONTIGUOUS shorts at
// row*S + quad*(K/4): pure ds_read_b128, 16B-aligned. Strides 40/72/136 shorts
// (80/144/272 B) give 2-way bank aliasing only (free per m136).
#define S1 40     // lw1  [128][40]  K=32  (k>=28 zero)
#define S2 136    // lw2/ld2 [..][136] K=128
#define SC 72     // lcb/ld1 [..][72]  K=64
#define O_LW1 0
#define O_LW2 5120
#define O_LCB 13824
#define O_LD1 50688
#define O_LD2 59904
#define BLOB_SHORTS 64256
#define BLOB_F32    864
#define BLOB_BYTES  (BLOB_SHORTS * 2 + BLOB_F32 * 4)   // 131968
#define LDS_BYTES   BLOB_BYTES

// prep thread-index regions (e2 is 8-lane-parallel now)
#define E2_BASE   BLOB_SHORTS            // 4096 threads (8 per code)
#define B1_BASE   (BLOB_SHORTS + 4096)
#define B2_BASE   (B1_BASE + 128)
#define DB1_BASE  (B2_BASE + 64)
#define DB2_BASE  (DB1_BASE + 128)
#define PREP_END  (DB2_BASE + 32)

typedef short v4s __attribute__((ext_vector_type(4)));
typedef short v8s __attribute__((ext_vector_type(8)));
typedef float v4f __attribute__((ext_vector_type(4)));

union u2v4 { unsigned u[2]; v4s s; };

__device__ __forceinline__ unsigned short f2bf(float f) {   // RNE (prep only)
  unsigned u = __float_as_uint(f);
  u += 0x7fffu + ((u >> 16) & 1u);
  return (unsigned short)(u >> 16);
}
// pack two truncated bf16 (hi, lo) in ONE v_perm_b32 (truncation validated r7/r8)
__device__ __forceinline__ unsigned pk(float hi, float lo) {
  return __builtin_amdgcn_perm(__float_as_uint(hi), __float_as_uint(lo), 0x07060302u);
}
// unpack truncated-bf16 lanes of a pk'd u32 back to f32 (for the loss diff)
__device__ __forceinline__ float xf0(unsigned u) { return __uint_as_float(u << 16); }
__device__ __forceinline__ float xf1(unsigned u) { return __uint_as_float(u & 0xFFFF0000u); }

// 16x16x16 bf16 MFMA: k-index = quad*4+e matches C-layout row = quad*4+r,
// so one stage's accumulator (relu+pk'd) IS the next stage's B-fragment.
__device__ __forceinline__ v4f mfma16(v4s a, v4s b, v4f c) {
  return __builtin_amdgcn_mfma_f32_16x16x16bf16_1k(a, b, c, 0, 0, 0);
}
__device__ __forceinline__ v4s lo4(v8s v) { return __builtin_shufflevector(v, v, 0, 1, 2, 3); }
__device__ __forceinline__ v4s hi4(v8s v) { return __builtin_shufflevector(v, v, 4, 5, 6, 7); }

__device__ __forceinline__ v4s rlpk(v4f h) {   // relu + pack to bf16 chunk
  u2v4 c;
  c.u[0] = pk(fmaxf(h[1], 0.f), fmaxf(h[0], 0.f));
  c.u[1] = pk(fmaxf(h[3], 0.f), fmaxf(h[2], 0.f));
  return c.s;
}
__device__ __forceinline__ v4s zpk(v4f z) {    // pack to bf16 chunk
  u2v4 c; c.u[0] = pk(z[1], z[0]); c.u[1] = pk(z[3], z[2]); return c.s;
}
__device__ __forceinline__ v4s mkv(unsigned a, unsigned b) {
  u2v4 c; c.u[0] = a; c.u[1] = b; return c.s;
}
// argmin key: dist upper bits | 9-bit code (float order == dist order to 2^-14 rel;
// lowest code wins ties among equal upper bits)
__device__ __forceinline__ float kpack(float d, unsigned code) {
  return __uint_as_float((__float_as_uint(d) & 0xFFFFFE00u) | code);
}

// Blob layout (short offsets), quad-grouped, pad zeroed:
//   lw1 @0      [128 hid][40]   enc_w1^T   (K=32 slot, k>=28 zero)
//   lw2 @5120   [64  lat][136]  enc_w2^T   (K=128)
//   lcb @13824  [512 code][72]  bf16(-2*codebook) (K=64)
//   ld1 @50688  [128 hid][72]   bf16(-0.5*dec_w1^T)  (scale cancels -2q)
//   ld2 @59904  [32  n][136]    dec_w2^T   (rows n>=28 zero)
// f32 @ byte 128512: e2[512], b1[128], b2[64], db1[128], db2[32 pad0]
__global__ __launch_bounds__(256) void vq_prep(
    const float* __restrict__ ew1, const float* __restrict__ eb1,
    const float* __restrict__ ew2, const float* __restrict__ eb2,
    const float* __restrict__ cb,  const float* __restrict__ dw1,
    const float* __restrict__ db1, const float* __restrict__ dw2,
    const float* __restrict__ db2,
    unsigned short* __restrict__ blob) {
  int i = blockIdx.x * 256 + threadIdx.x;
  float* fb = (float*)(blob + BLOB_SHORTS);
  if (i < O_LW2) {                       // lw1 [128][40] K=32 per=8
    int row = i / S1, s = i % S1;
    unsigned short v = 0;
    if (s < 32) {
      int q = s >> 3, r2 = s & 7, j = r2 >> 2, e = r2 & 3;
      int k = j * 16 + q * 4 + e;
      if (k < IN_DIM) v = f2bf(ew1[k * HID + row]);
    }
    blob[i] = v;
  } else if (i < O_LCB) {                // lw2 [64][136] K=128 per=32
    int j2 = i - O_LW2; int row = j2 / S2, s = j2 % S2;
    unsigned short v = 0;
    if (s < 128) {
      int q = s >> 5, r2 = s & 31, j = r2 >> 2, e = r2 & 3;
      int k = j * 16 + q * 4 + e;
      v = f2bf(ew2[k * LAT + row]);
    }
    blob[i] = v;
  } else if (i < O_LD1) {                // lcb [512][72] K=64 per=16, = -2*cb
    int j2 = i - O_LCB; int row = j2 / SC, s = j2 % SC;
    unsigned short v = 0;
    if (s < 64) {
      int q = s >> 4, r2 = s & 15, j = r2 >> 2, e = r2 & 3;
      int k = j * 16 + q * 4 + e;
      v = f2bf(-2.0f * cb[row * LAT + k]);
    }
    blob[i] = v;
  } else if (i < O_LD2) {                // ld1 [128][72] = -0.5*dec_w1^T
    int j2 = i - O_LD1; int row = j2 / SC, s = j2 % SC;
    unsigned short v = 0;
    if (s < 64) {
      int q = s >> 4, r2 = s & 15, j = r2 >> 2, e = r2 & 3;
      int k = j * 16 + q * 4 + e;
      v = f2bf(-0.5f * dw1[k * HID + row]);
    }
    blob[i] = v;
  } else if (i < BLOB_SHORTS) {          // ld2 [32][136]
    int j2 = i - O_LD2; int row = j2 / S2, s = j2 % S2;
    unsigned short v = 0;
    if (s < 128 && row < IN_DIM) {
      int q = s >> 5, r2 = s & 31, j = r2 >> 2, e = r2 & 3;
      int k = j * 16 + q * 4 + e;
      v = f2bf(dw2[k * IN_DIM + row]);
    }
    blob[i] = v;
  } else if (i < B1_BASE) {              // e2: 8 lanes per code, float4 loads
    int j = i - E2_BASE;                 // 0..4095, wave-aligned region
    int c = j >> 3, l = j & 7;
    const float* p = cb + c * LAT + l * 8;
    float4 a = *(const float4*)p;
    float4 b = *(const float4*)(p + 4);
    float s = a.x * a.x + a.y * a.y + a.z * a.z + a.w * a.w
            + b.x * b.x + b.y * b.y + b.z * b.z + b.w * b.w;
    s += __shfl_xor(s, 1, 64);
    s += __shfl_xor(s, 2, 64);
    s += __shfl_xor(s, 4, 64);
    if (l == 0) fb[c] = s;
  } else if (i < B2_BASE) {
    fb[512 + (i - B1_BASE)] = eb1[i - B1_BASE];
  } else if (i < DB1_BASE) {
    fb[640 + (i - B2_BASE)] = eb2[i - B2_BASE];
  } else if (i < DB2_BASE) {
    fb[704 + (i - DB1_BASE)] = db1[i - DB1_BASE];
  } else if (i < PREP_END) {
    int k = i - DB2_BASE;
    fb[832 + k] = (k < IN_DIM) ? db2[k] : 0.f;
  }
}

// ---- 2-tile stage 1+2: x -> h -> z for tiles A and B, every weight fragment
// read ONCE and consumed by both tiles (halves S12 LDS traffic vs r13).
// jp-loop stays #pragma unroll 1: the back-edge caps scheduler load-hoisting
// (~6 v8s in flight), which is what kept r13 spill-free.
__device__ __forceinline__ void s12_pair(
    const unsigned short* __restrict__ L, const float* __restrict__ LF,
    int lm, int quad,
    v4s bxa_lo, v4s bxa_hi, v4s bxb_lo, v4s bxb_hi,
    v4s& zfa0, v4s& zfa1, v4s& zfa2, v4s& zfa3,
    v4s& zfb0, v4s& zfb1, v4s& zfb2, v4s& zfb3,
    float& z2a, float& z2b) {
  const int fw1 = O_LW1 + lm * S1 + quad * 8;
  const int fw2 = O_LW2 + lm * S2 + quad * 32;
  v4f za[4], zb[4];
#pragma unroll
  for (int nt = 0; nt < 4; ++nt) {
    v4f s = *(const v4f*)&LF[640 + nt * 16 + quad * 4];      // b2 seed (broadcast)
    za[nt] = s; zb[nt] = s;
  }
#pragma unroll 1
  for (int jp = 0; jp < 4; ++jp) {
    v4s hA0, hA1, hB0, hB1;
    {
      v8s w = *(const v8s*)&L[fw1 + (2 * jp) * (16 * S1)];
      v4f sd = *(const v4f*)&LF[512 + (2 * jp) * 16 + quad * 4];   // b1 seed
      v4f h = mfma16(lo4(w), bxa_lo, sd);
      h = mfma16(hi4(w), bxa_hi, h);
      hA0 = rlpk(h);
      h = mfma16(lo4(w), bxb_lo, sd);
      h = mfma16(hi4(w), bxb_hi, h);
      hB0 = rlpk(h);
    }
    {
      v8s w = *(const v8s*)&L[fw1 + (2 * jp + 1) * (16 * S1)];
      v4f sd = *(const v4f*)&LF[512 + (2 * jp + 1) * 16 + quad * 4];
      v4f h = mfma16(lo4(w), bxa_lo, sd);
      h = mfma16(hi4(w), bxa_hi, h);
      hA1 = rlpk(h);
      h = mfma16(lo4(w), bxb_lo, sd);
      h = mfma16(hi4(w), bxb_hi, h);
      hB1 = rlpk(h);
    }
#pragma unroll
    for (int nt = 0; nt < 4; ++nt) {
      v8s w2 = *(const v8s*)&L[fw2 + nt * (16 * S2) + jp * 8];
      za[nt] = mfma16(lo4(w2), hA0, za[nt]);
      za[nt] = mfma16(hi4(w2), hA1, za[nt]);
      zb[nt] = mfma16(lo4(w2), hB0, zb[nt]);
      zb[nt] = mfma16(hi4(w2), hB1, zb[nt]);
    }
  }
  z2a = za[0][0] * za[0][0] + za[0][1] * za[0][1] + za[0][2] * za[0][2] + za[0][3] * za[0][3]
      + za[1][0] * za[1][0] + za[1][1] * za[1][1] + za[1][2] * za[1][2] + za[1][3] * za[1][3]
      + za[2][0] * za[2][0] + za[2][1] * za[2][1] + za[2][2] * za[2][2] + za[2][3] * za[2][3]
      + za[3][0] * za[3][0] + za[3][1] * za[3][1] + za[3][2] * za[3][2] + za[3][3] * za[3][3];
  z2b = zb[0][0] * zb[0][0] + zb[0][1] * zb[0][1] + zb[0][2] * zb[0][2] + zb[0][3] * zb[0][3]
      + zb[1][0] * zb[1][0] + zb[1][1] * zb[1][1] + zb[1][2] * zb[1][2] + zb[1][3] * zb[1][3]
      + zb[2][0] * zb[2][0] + zb[2][1] * zb[2][1] + zb[2][2] * zb[2][2] + zb[2][3] * zb[2][3]
      + zb[3][0] * zb[3][0] + zb[3][1] * zb[3][1] + zb[3][2] * zb[3][2] + zb[3][3] * zb[3][3];
  zfa0 = zpk(za[0]); zfa1 = zpk(za[1]); zfa2 = zpk(za[2]); zfa3 = zpk(za[3]);
  zfb0 = zpk(zb[0]); zfb1 = zpk(zb[1]); zfb2 = zpk(zb[2]); zfb3 = zpk(zb[3]);
}

// ---- 2-tile stage 5+6: q -> hd -> recon for both tiles, weight fragments
// shared; includes stores + loss (x from bf16 packs).
__device__ __forceinline__ void s56_pair(
    const unsigned short* __restrict__ L, const float* __restrict__ LF,
    int lm, int quad, int codeA, int codeB,
    unsigned xa0, unsigned xa1, unsigned xa2, unsigned xa3,
    unsigned xb0, unsigned xb1, unsigned xb2, unsigned xb3,
    float* __restrict__ orowA, float* __restrict__ orowB, float& racc) {
  const int fd1 = O_LD1 + lm * SC + quad * 16;
  const int fd2 = O_LD2 + lm * S2 + quad * 32;
  const int gA = O_LCB + codeA * SC + quad * 16;   // -2q rows (wave-uniform code)
  const int gB = O_LCB + codeB * SC + quad * 16;
  v8s qa0 = *(const v8s*)&L[gA];
  v8s qa1 = *(const v8s*)&L[gA + 8];
  v8s qb0 = *(const v8s*)&L[gB];
  v8s qb1 = *(const v8s*)&L[gB + 8];
  v4f a6a[2], a6b[2];
#pragma unroll
  for (int nt = 0; nt < 2; ++nt) {
    v4f s = *(const v4f*)&LF[832 + nt * 16 + quad * 4];      // db2 seed
    a6a[nt] = s; a6b[nt] = s;
  }
#pragma unroll 1
  for (int jp = 0; jp < 4; ++jp) {
    v4s hA0, hA1, hB0, hB1;
#pragma unroll
    for (int jj = 0; jj < 2; ++jj) {
      int j = 2 * jp + jj;
      v8s d0 = *(const v8s*)&L[fd1 + j * (16 * SC)];
      v8s d1 = *(const v8s*)&L[fd1 + j * (16 * SC) + 8];
      v4f sd = *(const v4f*)&LF[704 + j * 16 + quad * 4];    // db1 seed
      v4f h = mfma16(lo4(d0), lo4(qa0), sd);
      h = mfma16(hi4(d0), hi4(qa0), h);
      h = mfma16(lo4(d1), lo4(qa1), h);
      h = mfma16(hi4(d1), hi4(qa1), h);
      v4s ha = rlpk(h);
      h = mfma16(lo4(d0), lo4(qb0), sd);
      h = mfma16(hi4(d0), hi4(qb0), h);
      h = mfma16(lo4(d1), lo4(qb1), h);
      h = mfma16(hi4(d1), hi4(qb1), h);
      v4s hb = rlpk(h);
      if (jj == 0) { hA0 = ha; hB0 = hb; } else { hA1 = ha; hB1 = hb; }
    }
#pragma unroll
    for (int nt = 0; nt < 2; ++nt) {
      v8s w6 = *(const v8s*)&L[fd2 + nt * (16 * S2) + jp * 8];
      a6a[nt] = mfma16(lo4(w6), hA0, a6a[nt]);
      a6a[nt] = mfma16(hi4(w6), hA1, a6a[nt]);
      a6b[nt] = mfma16(lo4(w6), hB0, a6b[nt]);
      a6b[nt] = mfma16(hi4(w6), hB1, a6b[nt]);
    }
  }
  *(float4*)(orowA + quad * 4) = (float4){a6a[0][0], a6a[0][1], a6a[0][2], a6a[0][3]};
  *(float4*)(orowB + quad * 4) = (float4){a6b[0][0], a6b[0][1], a6b[0][2], a6b[0][3]};
  if (quad < 3) {
    *(float4*)(orowA + 16 + quad * 4) = (float4){a6a[1][0], a6a[1][1], a6a[1][2], a6a[1][3]};
    *(float4*)(orowB + 16 + quad * 4) = (float4){a6b[1][0], a6b[1][1], a6b[1][2], a6b[1][3]};
  }
  float d;
  d = a6a[0][0] - xf0(xa0); racc += d * d;
  d = a6a[0][1] - xf1(xa0); racc += d * d;
  d = a6a[0][2] - xf0(xa1); racc += d * d;
  d = a6a[0][3] - xf1(xa1); racc += d * d;
  d = a6a[1][0] - xf0(xa2); racc += d * d;   // quad3: a6[1]==0 and x==0
  d = a6a[1][1] - xf1(xa2); racc += d * d;
  d = a6a[1][2] - xf0(xa3); racc += d * d;
  d = a6a[1][3] - xf1(xa3); racc += d * d;
  d = a6b[0][0] - xf0(xb0); racc += d * d;
  d = a6b[0][1] - xf1(xb0); racc += d * d;
  d = a6b[0][2] - xf0(xb1); racc += d * d;
  d = a6b[0][3] - xf1(xb1); racc += d * d;
  d = a6b[1][0] - xf0(xb2); racc += d * d;
  d = a6b[1][1] - xf1(xb2); racc += d * d;
  d = a6b[1][2] - xf0(xb3); racc += d * d;
  d = a6b[1][3] - xf1(xb3); racc += d * d;
}

// ---------------- fused main kernel ----------------
// Round-14: r13 proved spill-free at 60 VGPRs (FETCH/WRITE = pure x/out) and
// exposed the real limiter: LDS throughput -- 16 waves/CU each re-read the
// same weight tables (~164 b128/sweep at ~12cyc => ~26us/CU floor + latency).
// This round shares every S12/S56 weight fragment across BOTH batch tiles
// (argmin already shared): 164 -> ~120 b128/sweep, and each fragment feeds 2x
// the MFMA work (better latency hiding). The unroll-1 jp back-edges -- the
// mechanism that prevented r11/r12's scheduler-hoist spills -- are retained.
__global__ __attribute__((amdgpu_flat_work_group_size(1024, 1024)))
__attribute__((amdgpu_waves_per_eu(4, 4)))
void vq_main(
    const float* __restrict__ x,
    const unsigned short* __restrict__ blob,
    float* __restrict__ out, float* __restrict__ partials) {

  extern __shared__ __align__(16) char smem[];
  const unsigned short* L = (const unsigned short*)smem;
  const float*         LF = (const float*)(smem + BLOB_SHORTS * 2);

  const int tid  = threadIdx.x;
  const int wave = tid >> 6;
  const int lane = tid & 63;
  const int quad = lane >> 4;
  const int lm   = lane & 15;

  // ---- stage tables into LDS (one-time) ----
  {
    const float4* src = (const float4*)blob;
    float4* dst = (float4*)smem;
#pragma unroll
    for (int it = 0; it < 9; ++it) {
      int idx = it * 1024 + tid;
      if (idx < BLOB_BYTES / 16) dst[idx] = src[idx];
    }
  }
  __syncthreads();

  const int rbase = blockIdx.x * 1024 + wave * 64;
  float racc = 0.f, vqacc = 0.f;

#pragma unroll 1
  for (int sw = 0; sw < 2; ++sw) {
    const int r0 = rbase + sw * 32;

    // ---- x load -> packed bf16 only (f32 temps die immediately) ----
    unsigned xa0, xa1, xa2, xa3, xb0, xb1, xb2, xb3;
    {
      const float* xpa = x + (size_t)(r0 + lm) * IN_DIM;
      const float* xpb = x + (size_t)(r0 + 16 + lm) * IN_DIM;
      float4 t = *(const float4*)(xpa + quad * 4);
      xa0 = pk(t.y, t.x); xa1 = pk(t.w, t.z);
      t = (quad < 3) ? *(const float4*)(xpa + 16 + quad * 4) : (float4){0.f, 0.f, 0.f, 0.f};
      xa2 = pk(t.y, t.x); xa3 = pk(t.w, t.z);
      t = *(const float4*)(xpb + quad * 4);
      xb0 = pk(t.y, t.x); xb1 = pk(t.w, t.z);
      t = (quad < 3) ? *(const float4*)(xpb + 16 + quad * 4) : (float4){0.f, 0.f, 0.f, 0.f};
      xb2 = pk(t.y, t.x); xb3 = pk(t.w, t.z);
    }

    // ---- stages 1+2, tiles A+B together (fragments shared) ----
    v4s zfa0, zfa1, zfa2, zfa3, zfb0, zfb1, zfb2, zfb3;
    float z2a, z2b;
    s12_pair(L, LF, lm, quad,
             mkv(xa0, xa1), mkv(xa2, xa3), mkv(xb0, xb1), mkv(xb2, xb3),
             zfa0, zfa1, zfa2, zfa3, zfb0, zfb1, zfb2, zfb3, z2a, z2b);
    __builtin_amdgcn_sched_barrier(0);

    // ---- argmin: dist^T = e2 + (-2e)·z; cb fragments SHARED by both tiles ----
    const int fcb = O_LCB + lm * SC + quad * 16;
    float bkA = __uint_as_float(0x7f7fffffu);
    float bkB = bkA;
#pragma unroll 2
    for (int ct = 0; ct < 32; ++ct) {
      v8s c0 = *(const v8s*)&L[fcb + ct * (16 * SC)];        // chunks 0,1
      v8s c1 = *(const v8s*)&L[fcb + ct * (16 * SC) + 8];    // chunks 2,3
      v4f sd = *(const v4f*)&LF[ct * 16 + quad * 4];         // e2 seed
      v4f dA = mfma16(lo4(c0), zfa0, sd);
      dA = mfma16(hi4(c0), zfa1, dA);
      dA = mfma16(lo4(c1), zfa2, dA);
      dA = mfma16(hi4(c1), zfa3, dA);
      v4f dB = mfma16(lo4(c0), zfb0, sd);
      dB = mfma16(hi4(c0), zfb1, dB);
      dB = mfma16(lo4(c1), zfb2, dB);
      dB = mfma16(hi4(c1), zfb3, dB);
      unsigned cbase = (unsigned)(ct * 16 + quad * 4);
      bkA = fminf(bkA, fminf(fminf(kpack(dA[0], cbase), kpack(dA[1], cbase + 1)),
                             fminf(kpack(dA[2], cbase + 2), kpack(dA[3], cbase + 3))));
      bkB = fminf(bkB, fminf(fminf(kpack(dB[0], cbase), kpack(dB[1], cbase + 1)),
                             fminf(kpack(dB[2], cbase + 2), kpack(dB[3], cbase + 3))));
    }

    // ---- cross-quad argmin + z2 reduce ----
#pragma unroll
    for (int off = 16; off < 64; off <<= 1) {
      bkA = fminf(bkA, __shfl_xor(bkA, off, 64));
      bkB = fminf(bkB, __shfl_xor(bkB, off, 64));
      z2a += __shfl_xor(z2a, off, 64);
      z2b += __shfl_xor(z2b, off, 64);
    }
    unsigned ka = __float_as_uint(bkA), kb = __float_as_uint(bkB);
    int codeA = (int)(ka & 511u), codeB = (int)(kb & 511u);
    if (quad == 0)
      vqacc += z2a + __uint_as_float(ka & 0xFFFFFE00u)
             + z2b + __uint_as_float(kb & 0xFFFFFE00u);      // ||z-q||^2
    __builtin_amdgcn_sched_barrier(0);

    // ---- stages 5+6 + store + loss, tiles A+B together ----
    s56_pair(L, LF, lm, quad, codeA, codeB,
             xa0, xa1, xa2, xa3, xb0, xb1, xb2, xb3,
             out + (size_t)(r0 + lm) * IN_DIM,
             out + (size_t)(r0 + 16 + lm) * IN_DIM, racc);
    __builtin_amdgcn_sched_barrier(0);
  }

  // ---- per-wave butterfly, per-wave partial store (no atomics) ----
#pragma unroll
  for (int off = 1; off < 64; off <<= 1) {
    racc  += __shfl_xor(racc, off, 64);
    vqacc += __shfl_xor(vqacc, off, 64);
  }
  if (lane == 0) {
    size_t w = (size_t)blockIdx.x * WVS + wave;
    partials[w * 2]     = racc;
    partials[w * 2 + 1] = vqacc;
  }
}

// ---------------- finalize: reduce per-wave partials, write scalars ----------------
__global__ __launch_bounds__(256) void vq_fin(const float* __restrict__ partials,
                                              float* __restrict__ out) {
  float r = 0.f, v = 0.f;
  for (int i = threadIdx.x; i < NWAVE; i += 256) {
    r += partials[2 * i];
    v += partials[2 * i + 1];
  }
#pragma unroll
  for (int off = 1; off < 64; off <<= 1) {
    r += __shfl_xor(r, off, 64);
    v += __shfl_xor(v, off, 64);
  }
  __shared__ float s[4][2];
  int w = threadIdx.x >> 6;
  if ((threadIdx.x & 63) == 0) { s[w][0] = r; s[w][1] = v; }
  __syncthreads();
  if (threadIdx.x == 0) {
    float R = s[0][0] + s[1][0] + s[2][0] + s[3][0];
    float V = s[0][1] + s[1][1] + s[2][1] + s[3][1];
    out[7340032] = R * (1.0f / 7340032.0f);          // recon_loss = S / (B*28)
    out[7340033] = V * (1.25f / 16777216.0f);        // vq_loss = 1.25 * S / (B*64)
  }
}

extern "C" void kernel_launch(void* const* d_in, const int* in_sizes, int n_in,
                              void* d_out, int out_size, void* d_ws, size_t ws_size,
                              hipStream_t stream) {
  const float* x   = (const float*)d_in[0];
  const float* ew1 = (const float*)d_in[1];
  const float* eb1 = (const float*)d_in[2];
  const float* ew2 = (const float*)d_in[3];
  const float* eb2 = (const float*)d_in[4];
  const float* cb  = (const float*)d_in[5];
  const float* dw1 = (const float*)d_in[6];
  const float* db1 = (const float*)d_in[7];
  const float* dw2 = (const float*)d_in[8];
  const float* db2 = (const float*)d_in[9];

  char* ws = (char*)d_ws;
  unsigned short* blob = (unsigned short*)(ws + 0);   // 131968 B
  float* partials = (float*)(ws + 132096);            // 32768 B (4096*2 f32)

  float* out = (float*)d_out;

  // allow >64 KB dynamic LDS (gfx950 workgroup max is 160 KB)
  (void)hipFuncSetAttribute((const void*)vq_main,
                            hipFuncAttributeMaxDynamicSharedMemorySize, LDS_BYTES);

  vq_prep<<<(PREP_END + 255) / 256, 256, 0, stream>>>(
      ew1, eb1, ew2, eb2, cb, dw1, db1, dw2, db2, blob);
  vq_main<<<NBLK, 1024, LDS_BYTES, stream>>>(x, blob, out, partials);
  vq_fin<<<1, 256, 0, stream>>>(partials, out);
}